// Round 1
// baseline (2737.515 us; speedup 1.0000x reference)
//
#include <hip/hip_runtime.h>
#include <cmath>

namespace {

constexpr int B_ = 2;
constexpr int T_ = 2048;
constexpr int C_ = 1024;
constexpr int H_ = 16;
constexpr int D_ = 64;

// ---------------------------------------------------------------------------
// Y[m][n] = sum_k A[m][k] * W[n][k]  (+ bias[n])
// A: M x K row-major, W: N x K row-major (torch Linear: y = x @ W^T)
// 64x64 tile, BK=16, 256 threads, 4x4 register blocking.
// ---------------------------------------------------------------------------
__global__ __launch_bounds__(256)
void gemm_nt(const float* __restrict__ A, const float* __restrict__ W,
             float* __restrict__ Y, const float* __restrict__ bias,
             int M, int N, int K) {
  constexpr int BM = 64, BN = 64, BK = 16;
  __shared__ float As[BK][BM];   // k-major so compute reads are float4
  __shared__ float Ws[BK][BN];

  const int tid = threadIdx.x;
  const int mbase = blockIdx.y * BM;
  const int nbase = blockIdx.x * BN;
  const int tx = tid & 15;        // n sub-tile
  const int ty = tid >> 4;        // m sub-tile
  const int lm = tid >> 2;        // 0..63 : row loaded by this thread
  const int lk = (tid & 3) * 4;   // 0,4,8,12 : k offset (float4)

  const float* Ap = A + (size_t)(mbase + lm) * K + lk;
  const float* Wp = W + (size_t)(nbase + lm) * K + lk;

  float acc[4][4] = {};

  for (int k0 = 0; k0 < K; k0 += BK) {
    const float4 av = *(const float4*)(Ap + k0);
    const float4 wv = *(const float4*)(Wp + k0);
    __syncthreads();   // protect LDS from previous iteration's readers
    As[lk + 0][lm] = av.x; As[lk + 1][lm] = av.y;
    As[lk + 2][lm] = av.z; As[lk + 3][lm] = av.w;
    Ws[lk + 0][lm] = wv.x; Ws[lk + 1][lm] = wv.y;
    Ws[lk + 2][lm] = wv.z; Ws[lk + 3][lm] = wv.w;
    __syncthreads();
#pragma unroll
    for (int k = 0; k < BK; ++k) {
      const float4 a4 = *(const float4*)&As[k][ty * 4];
      const float4 b4 = *(const float4*)&Ws[k][tx * 4];
      const float a[4] = {a4.x, a4.y, a4.z, a4.w};
      const float b[4] = {b4.x, b4.y, b4.z, b4.w};
#pragma unroll
      for (int i = 0; i < 4; ++i)
#pragma unroll
        for (int j = 0; j < 4; ++j)
          acc[i][j] += a[i] * b[j];
    }
  }

  const int m0 = mbase + ty * 4;
  const int n0 = nbase + tx * 4;
#pragma unroll
  for (int i = 0; i < 4; ++i) {
    float4 v;
    v.x = acc[i][0]; v.y = acc[i][1]; v.z = acc[i][2]; v.w = acc[i][3];
    if (bias != nullptr) {
      v.x += bias[n0 + 0]; v.y += bias[n0 + 1];
      v.z += bias[n0 + 2]; v.w += bias[n0 + 3];
    }
    *(float4*)(Y + (size_t)(m0 + i) * N + n0) = v;
  }
}

// ---------------------------------------------------------------------------
// Fused attention with softmax over the HEAD axis.
// Block = (b, 16 q rows), 256 threads = (h, q) pairs; thread (h,q) owns
// Q[b,q,h*64:(h+1)*64] in registers and accumulates O[b,h,q,0:64].
// Per 8-row k-tile: stage K rows -> scores (x8 = sqrt(D) quirk) -> softmax
// across h in LDS -> restage same buffer with V rows -> accumulate.
// LDS rows stored as [kk][h][68] (pad 4) to avoid 4-way bank conflicts on
// the per-head 64-float slices (64 % 32 == 0 otherwise).
// ---------------------------------------------------------------------------
__global__ __launch_bounds__(256)
void attn_fused(const float* __restrict__ Q, const float* __restrict__ K,
                const float* __restrict__ V, float* __restrict__ AO) {
  constexpr int TQ = 16;          // q rows per block
  constexpr int KT = 8;           // k rows per tile
  constexpr int DP = D_ + 4;      // padded head slice (68 floats)
  __shared__ float buf[KT][H_ * DP];   // 8 * 1088 * 4B = 34.8 KB (K then V)
  __shared__ float Ss[H_][TQ][KT];     // 8 KB score/prob tile

  const int tid = threadIdx.x;
  const int b  = blockIdx.x / (T_ / TQ);
  const int qt = blockIdx.x % (T_ / TQ);
  const int h = tid >> 4;
  const int q = tid & 15;

  // Q slice in registers: 16 x float4 = 64 floats
  const float* qrow = Q + ((size_t)b * T_ + qt * TQ + q) * C_ + h * D_;
  float4 q4[16];
#pragma unroll
  for (int i = 0; i < 16; ++i) q4[i] = ((const float4*)qrow)[i];

  float4 o4[16];
#pragma unroll
  for (int i = 0; i < 16; ++i) { o4[i].x = 0.f; o4[i].y = 0.f; o4[i].z = 0.f; o4[i].w = 0.f; }

  const float* Kb = K + (size_t)b * T_ * C_;
  const float* Vb = V + (size_t)b * T_ * C_;

  // staging map: thread writes float4 #tid of each row; col = 4*tid lies
  // entirely inside head col/64, padded address = (col/64)*DP + (col%64)
  const int scol = tid * 4;
  const int soff = (scol / D_) * DP + (scol % D_);

  for (int k0 = 0; k0 < T_; k0 += KT) {
    __syncthreads();  // previous PV reads of buf done
#pragma unroll
    for (int it = 0; it < KT; ++it)
      *(float4*)&buf[it][soff] = *(const float4*)(Kb + (size_t)(k0 + it) * C_ + scol);
    __syncthreads();

    // scores for this thread's (h, q) over KT keys
#pragma unroll
    for (int kk = 0; kk < KT; ++kk) {
      const float4* krow = (const float4*)&buf[kk][h * DP];
      float sx = 0.f, sy = 0.f, sz = 0.f, sw = 0.f;
#pragma unroll
      for (int i = 0; i < 16; ++i) {
        const float4 kv = krow[i];
        sx += q4[i].x * kv.x; sy += q4[i].y * kv.y;
        sz += q4[i].z * kv.z; sw += q4[i].w * kv.w;
      }
      Ss[h][q][kk] = (sx + sy + sz + sw) * 8.0f;  // quirk: * sqrt(D)
    }
    __syncthreads();

    // restage buf with V rows (scores already consumed)
#pragma unroll
    for (int it = 0; it < KT; ++it)
      *(float4*)&buf[it][soff] = *(const float4*)(Vb + (size_t)(k0 + it) * C_ + scol);

    // softmax over the 16 heads for each (q, kk): 128 threads, one (q,kk) each
    if (tid < TQ * KT) {
      const int sq = tid / KT, sk = tid % KT;
      float mx = -3.4e38f;
#pragma unroll
      for (int hh = 0; hh < H_; ++hh) mx = fmaxf(mx, Ss[hh][sq][sk]);
      float e[H_];
      float sum = 0.f;
#pragma unroll
      for (int hh = 0; hh < H_; ++hh) {
        e[hh] = __expf(Ss[hh][sq][sk] - mx);
        sum += e[hh];
      }
      const float inv = 1.0f / sum;
#pragma unroll
      for (int hh = 0; hh < H_; ++hh) Ss[hh][sq][sk] = e[hh] * inv;
    }
    __syncthreads();

    // O += P @ V-tile
#pragma unroll
    for (int kk = 0; kk < KT; ++kk) {
      const float p = Ss[h][q][kk];
      const float4* vrow = (const float4*)&buf[kk][h * DP];
#pragma unroll
      for (int i = 0; i < 16; ++i) {
        const float4 vv = vrow[i];
        o4[i].x += p * vv.x; o4[i].y += p * vv.y;
        o4[i].z += p * vv.z; o4[i].w += p * vv.w;
      }
    }
  }

  float* aorow = AO + ((size_t)b * T_ + qt * TQ + q) * C_ + h * D_;
#pragma unroll
  for (int i = 0; i < 16; ++i) ((float4*)aorow)[i] = o4[i];
}

}  // namespace

extern "C" void kernel_launch(void* const* d_in, const int* in_sizes, int n_in,
                              void* d_out, int out_size, void* d_ws, size_t ws_size,
                              hipStream_t stream) {
  const float* xq = (const float*)d_in[0];
  const float* xk = (const float*)d_in[1];
  const float* xv = (const float*)d_in[2];
  const float* Wq = (const float*)d_in[3];
  const float* Wk = (const float*)d_in[4];
  const float* Wv = (const float*)d_in[5];
  const float* Wo = (const float*)d_in[6];
  const float* bo = (const float*)d_in[7];
  float* out = (float*)d_out;

  const size_t nBTC = (size_t)B_ * T_ * C_;   // 4M elements, 16 MB fp32
  float* Q  = (float*)d_ws;
  float* Kp = Q + nBTC;
  float* Vp = Kp + nBTC;
  float* AO = Vp + nBTC;                      // total ws use: 64 MB

  const int M = B_ * T_;                      // 4096
  dim3 ggrid(C_ / 64, M / 64);                // 16 x 64 = 1024 blocks
  dim3 gblk(256);

  gemm_nt<<<ggrid, gblk, 0, stream>>>(xq, Wq, Q,  nullptr, M, C_, C_);
  gemm_nt<<<ggrid, gblk, 0, stream>>>(xk, Wk, Kp, nullptr, M, C_, C_);
  gemm_nt<<<ggrid, gblk, 0, stream>>>(xv, Wv, Vp, nullptr, M, C_, C_);

  dim3 agrid(B_ * (T_ / 16));                 // 256 blocks
  attn_fused<<<agrid, gblk, 0, stream>>>(Q, Kp, Vp, AO);

  gemm_nt<<<ggrid, gblk, 0, stream>>>(AO, Wo, out, bo, M, C_, C_);
}

// Round 2
// 2102.848 us; speedup vs baseline: 1.3018x; 1.3018x over previous
//
#include <hip/hip_runtime.h>
#include <cmath>

namespace {

constexpr int B_ = 2;
constexpr int T_ = 2048;
constexpr int C_ = 1024;
constexpr int H_ = 16;
constexpr int D_ = 64;

// ---------------------------------------------------------------------------
// Y[m][n] = sum_k A[m][k] * W[n][k]  (+ bias[n])
// ---------------------------------------------------------------------------
__global__ __launch_bounds__(256)
void gemm_nt(const float* __restrict__ A, const float* __restrict__ W,
             float* __restrict__ Y, const float* __restrict__ bias,
             int M, int N, int K) {
  constexpr int BM = 64, BN = 64, BK = 16;
  __shared__ float As[BK][BM];
  __shared__ float Ws[BK][BN];

  const int tid = threadIdx.x;
  const int mbase = blockIdx.y * BM;
  const int nbase = blockIdx.x * BN;
  const int tx = tid & 15;
  const int ty = tid >> 4;
  const int lm = tid >> 2;
  const int lk = (tid & 3) * 4;

  const float* Ap = A + (size_t)(mbase + lm) * K + lk;
  const float* Wp = W + (size_t)(nbase + lm) * K + lk;

  float acc[4][4] = {};

  for (int k0 = 0; k0 < K; k0 += BK) {
    const float4 av = *(const float4*)(Ap + k0);
    const float4 wv = *(const float4*)(Wp + k0);
    __syncthreads();
    As[lk + 0][lm] = av.x; As[lk + 1][lm] = av.y;
    As[lk + 2][lm] = av.z; As[lk + 3][lm] = av.w;
    Ws[lk + 0][lm] = wv.x; Ws[lk + 1][lm] = wv.y;
    Ws[lk + 2][lm] = wv.z; Ws[lk + 3][lm] = wv.w;
    __syncthreads();
#pragma unroll
    for (int k = 0; k < BK; ++k) {
      const float4 a4 = *(const float4*)&As[k][ty * 4];
      const float4 b4 = *(const float4*)&Ws[k][tx * 4];
      const float a[4] = {a4.x, a4.y, a4.z, a4.w};
      const float b[4] = {b4.x, b4.y, b4.z, b4.w};
#pragma unroll
      for (int i = 0; i < 4; ++i)
#pragma unroll
        for (int j = 0; j < 4; ++j)
          acc[i][j] += a[i] * b[j];
    }
  }

  const int m0 = mbase + ty * 4;
  const int n0 = nbase + tx * 4;
#pragma unroll
  for (int i = 0; i < 4; ++i) {
    float4 v;
    v.x = acc[i][0]; v.y = acc[i][1]; v.z = acc[i][2]; v.w = acc[i][3];
    if (bias != nullptr) {
      v.x += bias[n0 + 0]; v.y += bias[n0 + 1];
      v.z += bias[n0 + 2]; v.w += bias[n0 + 3];
    }
    *(float4*)(Y + (size_t)(m0 + i) * N + n0) = v;
  }
}

// ---------------------------------------------------------------------------
// Fused head-softmax attention, restructured for occupancy:
//   thread = (h, q, dh): 16 heads x 16 q-rows x 2 D-halves = 512 threads.
//   split-k x2: block handles 1024 k-rows; partial O accumulated into AO
//   via fp32 atomicAdd (AO zeroed beforehand). Softmax over heads is local
//   to each (q,k) so split-k is exact.
// Thread (h,q,dh) holds Q[b,q,h*64+dh*32 .. +32) and the matching O half in
// registers (32+32 VGPRs). Pair-reduce of half-dots via __shfl_xor lane^1.
// ---------------------------------------------------------------------------
__global__ __launch_bounds__(512, 4)
void attn_fused(const float* __restrict__ Q, const float* __restrict__ K,
                const float* __restrict__ V, float* __restrict__ AO) {
  constexpr int SPLIT = 2;
  constexpr int TQ = 16;          // q rows per block
  constexpr int KT = 8;           // k rows per tile
  constexpr int DP = D_ + 4;      // padded head slice (68 floats)
  __shared__ float buf[KT][H_ * DP];     // 34.8 KB (K rows, then V rows)
  __shared__ float Ss[H_][TQ][KT + 1];   // 9.2 KB, inner pad kills 8-way conflict

  const int tid = threadIdx.x;
  const int bq    = blockIdx.x / SPLIT;
  const int split = blockIdx.x % SPLIT;
  const int b  = bq / (T_ / TQ);
  const int qt = bq % (T_ / TQ);
  const int dh = tid & 1;         // which 32-float half of the head dim
  const int q  = (tid >> 1) & 15;
  const int h  = tid >> 5;

  // Q half-slice in registers: 8 x float4 = 32 floats
  const float* qrow = Q + ((size_t)b * T_ + qt * TQ + q) * C_ + h * D_ + dh * 32;
  float4 q4[8];
#pragma unroll
  for (int i = 0; i < 8; ++i) q4[i] = ((const float4*)qrow)[i];

  float4 o4[8];
#pragma unroll
  for (int i = 0; i < 8; ++i) { o4[i].x = 0.f; o4[i].y = 0.f; o4[i].z = 0.f; o4[i].w = 0.f; }

  const float* Kb = K + (size_t)b * T_ * C_;
  const float* Vb = V + (size_t)b * T_ * C_;

  // staging map: 8 rows x 256 float4 = 2048 float4s; thread handles 4 of them
  int srow[4], soff[4], gcol[4];
#pragma unroll
  for (int j = 0; j < 4; ++j) {
    const int idx = tid + j * 512;
    srow[j] = idx >> 8;
    const int scol = (idx & 255) * 4;
    soff[j] = (scol / D_) * DP + (scol % D_);
    gcol[j] = scol;
  }

  const int k_lo = split * (T_ / SPLIT);
  const int k_hi = k_lo + (T_ / SPLIT);

  for (int k0 = k_lo; k0 < k_hi; k0 += KT) {
    __syncthreads();  // previous PV reads of buf done
#pragma unroll
    for (int j = 0; j < 4; ++j)
      *(float4*)&buf[srow[j]][soff[j]] =
          *(const float4*)(Kb + (size_t)(k0 + srow[j]) * C_ + gcol[j]);
    __syncthreads();

    // scores: half-dot over 32 dims, pair-reduce across dh via lane^1
#pragma unroll
    for (int kk = 0; kk < KT; ++kk) {
      const float4* krow = (const float4*)&buf[kk][h * DP + dh * 32];
      float sx = 0.f, sy = 0.f, sz = 0.f, sw = 0.f;
#pragma unroll
      for (int i = 0; i < 8; ++i) {
        const float4 kv = krow[i];
        sx += q4[i].x * kv.x; sy += q4[i].y * kv.y;
        sz += q4[i].z * kv.z; sw += q4[i].w * kv.w;
      }
      float s = (sx + sy) + (sz + sw);
      s += __shfl_xor(s, 1);
      if (dh == 0) Ss[h][q][kk] = s * 8.0f;  // quirk: * sqrt(D)
    }
    __syncthreads();

    // restage buf with V rows (scores already consumed)
#pragma unroll
    for (int j = 0; j < 4; ++j)
      *(float4*)&buf[srow[j]][soff[j]] =
          *(const float4*)(Vb + (size_t)(k0 + srow[j]) * C_ + gcol[j]);

    // softmax over the 16 heads for each (q, kk): threads 0..127
    if (tid < TQ * KT) {
      const int sq = tid >> 3, sk = tid & 7;
      float mx = -3.4e38f;
#pragma unroll
      for (int hh = 0; hh < H_; ++hh) mx = fmaxf(mx, Ss[hh][sq][sk]);
      float e[H_];
      float sum = 0.f;
#pragma unroll
      for (int hh = 0; hh < H_; ++hh) {
        e[hh] = __expf(Ss[hh][sq][sk] - mx);
        sum += e[hh];
      }
      const float inv = 1.0f / sum;
#pragma unroll
      for (int hh = 0; hh < H_; ++hh) Ss[hh][sq][sk] = e[hh] * inv;
    }
    __syncthreads();

    // O += P @ V-tile (this thread's 32-float half)
#pragma unroll
    for (int kk = 0; kk < KT; ++kk) {
      const float p = Ss[h][q][kk];
      const float4* vrow = (const float4*)&buf[kk][h * DP + dh * 32];
#pragma unroll
      for (int i = 0; i < 8; ++i) {
        const float4 vv = vrow[i];
        o4[i].x += p * vv.x; o4[i].y += p * vv.y;
        o4[i].z += p * vv.z; o4[i].w += p * vv.w;
      }
    }
  }

  float* aorow = AO + ((size_t)b * T_ + qt * TQ + q) * C_ + h * D_ + dh * 32;
#pragma unroll
  for (int i = 0; i < 8; ++i) {
    atomicAdd(aorow + i * 4 + 0, o4[i].x);
    atomicAdd(aorow + i * 4 + 1, o4[i].y);
    atomicAdd(aorow + i * 4 + 2, o4[i].z);
    atomicAdd(aorow + i * 4 + 3, o4[i].w);
  }
}

}  // namespace

extern "C" void kernel_launch(void* const* d_in, const int* in_sizes, int n_in,
                              void* d_out, int out_size, void* d_ws, size_t ws_size,
                              hipStream_t stream) {
  const float* xq = (const float*)d_in[0];
  const float* xk = (const float*)d_in[1];
  const float* xv = (const float*)d_in[2];
  const float* Wq = (const float*)d_in[3];
  const float* Wk = (const float*)d_in[4];
  const float* Wv = (const float*)d_in[5];
  const float* Wo = (const float*)d_in[6];
  const float* bo = (const float*)d_in[7];
  float* out = (float*)d_out;

  const size_t nBTC = (size_t)B_ * T_ * C_;   // 4M elements, 16 MB fp32
  float* Q  = (float*)d_ws;
  float* Kp = Q + nBTC;
  float* Vp = Kp + nBTC;
  float* AO = Vp + nBTC;                      // total ws use: 64 MB

  const int M = B_ * T_;                      // 4096
  dim3 ggrid(C_ / 64, M / 64);
  dim3 gblk(256);

  gemm_nt<<<ggrid, gblk, 0, stream>>>(xq, Wq, Q,  nullptr, M, C_, C_);
  gemm_nt<<<ggrid, gblk, 0, stream>>>(xk, Wk, Kp, nullptr, M, C_, C_);
  gemm_nt<<<ggrid, gblk, 0, stream>>>(xv, Wv, Vp, nullptr, M, C_, C_);

  // zero AO for split-k atomic accumulation
  hipMemsetAsync(AO, 0, nBTC * sizeof(float), stream);

  dim3 agrid(B_ * (T_ / 16) * 2);             // 512 blocks (split-k x2)
  attn_fused<<<agrid, dim3(512), 0, stream>>>(Q, Kp, Vp, AO);

  gemm_nt<<<ggrid, gblk, 0, stream>>>(AO, Wo, out, bo, M, C_, C_);
}

// Round 3
// 1511.519 us; speedup vs baseline: 1.8111x; 1.3912x over previous
//
#include <hip/hip_runtime.h>
#include <cmath>

namespace {

constexpr int B_ = 2;
constexpr int T_ = 2048;
constexpr int C_ = 1024;
constexpr int H_ = 16;
constexpr int D_ = 64;

typedef _Float16 half8 __attribute__((ext_vector_type(8)));
typedef _Float16 half4 __attribute__((ext_vector_type(4)));
typedef float f32x4 __attribute__((ext_vector_type(4)));

// ---------------------------------------------------------------------------
// Y[m][n] = sum_k A[m][k] * W[n][k]; epilogue modes:
//   0: write f16 (Yh)            [V projection]
//   1: write f16 hi+lo (Yh, Yl)  [Q, K projections — Markidis split]
//   2: write fp32 + bias (Yf)    [output projection]
// ---------------------------------------------------------------------------
__global__ __launch_bounds__(256)
void gemm_nt(const float* __restrict__ A, const float* __restrict__ W,
             int M, int N, int K,
             float* __restrict__ Yf, const float* __restrict__ bias,
             _Float16* __restrict__ Yh, _Float16* __restrict__ Yl, int mode) {
  constexpr int BM = 64, BN = 64, BK = 16;
  __shared__ float As[BK][BM];
  __shared__ float Ws[BK][BN];

  const int tid = threadIdx.x;
  const int mbase = blockIdx.y * BM;
  const int nbase = blockIdx.x * BN;
  const int tx = tid & 15;
  const int ty = tid >> 4;
  const int lm = tid >> 2;
  const int lk = (tid & 3) * 4;

  const float* Ap = A + (size_t)(mbase + lm) * K + lk;
  const float* Wp = W + (size_t)(nbase + lm) * K + lk;

  float acc[4][4] = {};

  for (int k0 = 0; k0 < K; k0 += BK) {
    const float4 av = *(const float4*)(Ap + k0);
    const float4 wv = *(const float4*)(Wp + k0);
    __syncthreads();
    As[lk + 0][lm] = av.x; As[lk + 1][lm] = av.y;
    As[lk + 2][lm] = av.z; As[lk + 3][lm] = av.w;
    Ws[lk + 0][lm] = wv.x; Ws[lk + 1][lm] = wv.y;
    Ws[lk + 2][lm] = wv.z; Ws[lk + 3][lm] = wv.w;
    __syncthreads();
#pragma unroll
    for (int k = 0; k < BK; ++k) {
      const float4 a4 = *(const float4*)&As[k][ty * 4];
      const float4 b4 = *(const float4*)&Ws[k][tx * 4];
      const float a[4] = {a4.x, a4.y, a4.z, a4.w};
      const float b[4] = {b4.x, b4.y, b4.z, b4.w};
#pragma unroll
      for (int i = 0; i < 4; ++i)
#pragma unroll
        for (int j = 0; j < 4; ++j)
          acc[i][j] += a[i] * b[j];
    }
  }

  const int m0 = mbase + ty * 4;
  const int n0 = nbase + tx * 4;
#pragma unroll
  for (int i = 0; i < 4; ++i) {
    if (mode == 2) {
      float4 v;
      v.x = acc[i][0] + bias[n0 + 0];
      v.y = acc[i][1] + bias[n0 + 1];
      v.z = acc[i][2] + bias[n0 + 2];
      v.w = acc[i][3] + bias[n0 + 3];
      *(float4*)(Yf + (size_t)(m0 + i) * N + n0) = v;
    } else {
      half4 hi, lo;
#pragma unroll
      for (int j = 0; j < 4; ++j) {
        const float a = acc[i][j];
        const _Float16 h = (_Float16)a;
        hi[j] = h;
        lo[j] = (_Float16)(a - (float)h);
      }
      *(half4*)(Yh + (size_t)(m0 + i) * N + n0) = hi;
      if (mode == 1) *(half4*)(Yl + (size_t)(m0 + i) * N + n0) = lo;
    }
  }
}

// ---------------------------------------------------------------------------
// MFMA attention, softmax over the HEAD axis.
// Block = (b, 16 q rows), 256 threads = 4 waves; wave w owns heads 4w..4w+3.
// Per 16-key tile:
//   S = Q K^T via mfma_f32_16x16x32_f16 x3 (Markidis hi/lo: err ~ fp32),
//       K fragments read directly from global (64B/row granular, L1/L2).
//   head-softmax: per-wave max/sum partials through LDS (2 barriers/tile).
//   P -> wave-private LDS (C-layout -> B-frag layout, no barrier needed).
//   V staged transposed in LDS; O^T += V^T P^T via mfma_f32_16x16x16f16.
// ---------------------------------------------------------------------------
constexpr int VT_HSTRIDE = 2560;  // 64 d-rows * 40 B  (40 = 32+8 pad: banks 10d%32 distinct)
constexpr int VT_DSTRIDE = 40;
constexpr int P_BASE     = 40960;
constexpr int P_WSTRIDE  = 2560;  // 4 heads * 640
constexpr int P_HSTRIDE  = 640;   // 16 q * 40
constexpr int P_QSTRIDE  = 40;
constexpr int PMAX_BASE  = 51200;
constexpr int PSUM_BASE  = 55296;
constexpr int SMEM_BYTES = 59392;

__global__ __launch_bounds__(256, 1)
void attn_mfma(const _Float16* __restrict__ Qhp, const _Float16* __restrict__ Qlp,
               const _Float16* __restrict__ Khp, const _Float16* __restrict__ Klp,
               const _Float16* __restrict__ Vhp, float* __restrict__ AO) {
  __shared__ __align__(16) char smem[SMEM_BYTES];

  const int tid  = threadIdx.x;
  const int lane = tid & 63;
  const int w    = tid >> 6;
  const int l15  = lane & 15;
  const int quad = lane >> 4;

  const int b  = blockIdx.x >> 7;
  const int q0 = (blockIdx.x & 127) << 4;

  // Q fragments (A-layout: A[m=lane&15][k=quad*8+j]) for 4 heads x 2 K-halves
  const size_t qrow = ((size_t)b * T_ + q0 + l15) * C_;
  half8 qh[4][2], ql[4][2];
#pragma unroll
  for (int hl = 0; hl < 4; ++hl)
#pragma unroll
    for (int kk = 0; kk < 2; ++kk) {
      const int off = (w * 4 + hl) * 64 + kk * 32 + quad * 8;
      qh[hl][kk] = *(const half8*)(Qhp + qrow + off);
      ql[hl][kk] = *(const half8*)(Qlp + qrow + off);
    }

  f32x4 oacc[4][4];
#pragma unroll
  for (int hl = 0; hl < 4; ++hl)
#pragma unroll
    for (int mt = 0; mt < 4; ++mt)
      oacc[hl][mt] = (f32x4){0.f, 0.f, 0.f, 0.f};

  const int vrow0 = w * 4;  // this wave stages k-rows 4w..4w+3 of each V tile

  for (int k0 = 0; k0 < T_; k0 += 16) {
    // ---- scores (Markidis 3-product) ----
    f32x4 s[4];
#pragma unroll
    for (int hl = 0; hl < 4; ++hl) s[hl] = (f32x4){0.f, 0.f, 0.f, 0.f};
    const size_t krow = ((size_t)b * T_ + k0 + l15) * C_;
#pragma unroll
    for (int hl = 0; hl < 4; ++hl)
#pragma unroll
      for (int kk = 0; kk < 2; ++kk) {
        const int off = (w * 4 + hl) * 64 + kk * 32 + quad * 8;
        const half8 bh = *(const half8*)(Khp + krow + off);
        const half8 bl = *(const half8*)(Klp + krow + off);
        s[hl] = __builtin_amdgcn_mfma_f32_16x16x32_f16(qh[hl][kk], bh, s[hl], 0, 0, 0);
        s[hl] = __builtin_amdgcn_mfma_f32_16x16x32_f16(ql[hl][kk], bh, s[hl], 0, 0, 0);
        s[hl] = __builtin_amdgcn_mfma_f32_16x16x32_f16(qh[hl][kk], bl, s[hl], 0, 0, 0);
      }

    // quirk scale *sqrt(D)=8, per-wave head-max partials
#pragma unroll
    for (int r = 0; r < 4; ++r) {
      s[0][r] *= 8.f; s[1][r] *= 8.f; s[2][r] *= 8.f; s[3][r] *= 8.f;
      const float pm = fmaxf(fmaxf(s[0][r], s[1][r]), fmaxf(s[2][r], s[3][r]));
      ((float*)(smem + PMAX_BASE))[w * 256 + (quad * 4 + r) * 16 + l15] = pm;
    }
    __syncthreads();  // pmax visible; previous tile's V-fragment reads done

    // ---- stage V transposed: Vt[h][d][k16] ----
    {
      const size_t vbase = ((size_t)b * T_ + k0 + vrow0) * C_;
#pragma unroll
      for (int j = 0; j < 2; ++j) {
        const int cc = lane + 64 * j;        // 16B-chunk index 0..127
        const int h  = cc >> 3;
        const int d0 = (cc & 7) * 8;
        half8 v[4];
#pragma unroll
        for (int r = 0; r < 4; ++r)
          v[r] = *(const half8*)(Vhp + vbase + (size_t)r * C_ + cc * 8);
#pragma unroll
        for (int ss = 0; ss < 8; ++ss) {     // rotated scatter: banks spread
          const int i = (ss + lane) & 7;
          half4 pk; pk[0] = v[0][i]; pk[1] = v[1][i]; pk[2] = v[2][i]; pk[3] = v[3][i];
          *(half4*)(smem + h * VT_HSTRIDE + (d0 + i) * VT_DSTRIDE + vrow0 * 2) = pk;
        }
      }
    }

    // ---- head-softmax ----
    float e[4][4];
#pragma unroll
    for (int r = 0; r < 4; ++r) {
      const int cell = (quad * 4 + r) * 16 + l15;
      const float* pmx = (const float*)(smem + PMAX_BASE);
      const float gmax = fmaxf(fmaxf(pmx[cell], pmx[256 + cell]),
                               fmaxf(pmx[512 + cell], pmx[768 + cell]));
      float ps = 0.f;
#pragma unroll
      for (int hl = 0; hl < 4; ++hl) {
        e[hl][r] = __expf(s[hl][r] - gmax);
        ps += e[hl][r];
      }
      ((float*)(smem + PSUM_BASE))[w * 256 + cell] = ps;
    }
    __syncthreads();  // psum visible; V staged

#pragma unroll
    for (int r = 0; r < 4; ++r) {
      const int cell = (quad * 4 + r) * 16 + l15;
      const float* psm = (const float*)(smem + PSUM_BASE);
      const float inv = 1.f / (psm[cell] + psm[256 + cell] + psm[512 + cell] + psm[768 + cell]);
#pragma unroll
      for (int hl = 0; hl < 4; ++hl)
        *(_Float16*)(smem + P_BASE + w * P_WSTRIDE + hl * P_HSTRIDE
                     + (quad * 4 + r) * P_QSTRIDE + l15 * 2) = (_Float16)(e[hl][r] * inv);
    }

    // ---- O^T += V^T P^T (wave-private P; in-order DS, no barrier) ----
#pragma unroll
    for (int hl = 0; hl < 4; ++hl) {
      const half4 pfrag = *(const half4*)(smem + P_BASE + w * P_WSTRIDE + hl * P_HSTRIDE
                                          + l15 * P_QSTRIDE + quad * 8);
      const int h = w * 4 + hl;
#pragma unroll
      for (int mt = 0; mt < 4; ++mt) {
        const half4 vfrag = *(const half4*)(smem + h * VT_HSTRIDE
                                            + (mt * 16 + l15) * VT_DSTRIDE + quad * 8);
        oacc[hl][mt] = __builtin_amdgcn_mfma_f32_16x16x16f16(vfrag, pfrag, oacc[hl][mt], 0, 0, 0);
      }
    }
  }

  // O^T lane layout: col=q=l15, row=d=mt*16+quad*4+reg (reg-consecutive d -> float4)
  const size_t orow = ((size_t)b * T_ + q0 + l15) * C_;
#pragma unroll
  for (int hl = 0; hl < 4; ++hl)
#pragma unroll
    for (int mt = 0; mt < 4; ++mt) {
      float4 v;
      v.x = oacc[hl][mt][0]; v.y = oacc[hl][mt][1];
      v.z = oacc[hl][mt][2]; v.w = oacc[hl][mt][3];
      *(float4*)(AO + orow + (w * 4 + hl) * 64 + mt * 16 + quad * 4) = v;
    }
}

}  // namespace

extern "C" void kernel_launch(void* const* d_in, const int* in_sizes, int n_in,
                              void* d_out, int out_size, void* d_ws, size_t ws_size,
                              hipStream_t stream) {
  const float* xq = (const float*)d_in[0];
  const float* xk = (const float*)d_in[1];
  const float* xv = (const float*)d_in[2];
  const float* Wq = (const float*)d_in[3];
  const float* Wk = (const float*)d_in[4];
  const float* Wv = (const float*)d_in[5];
  const float* Wo = (const float*)d_in[6];
  const float* bo = (const float*)d_in[7];
  float* out = (float*)d_out;

  const size_t nBTC = (size_t)B_ * T_ * C_;  // 4M elements
  _Float16* Qh = (_Float16*)d_ws;            // 8 MB each
  _Float16* Ql = Qh + nBTC;
  _Float16* Kh = Ql + nBTC;
  _Float16* Kl = Kh + nBTC;
  _Float16* Vh = Kl + nBTC;
  float*    AO = (float*)(Vh + nBTC);        // 16 MB fp32; total ws = 56 MB

  const int M = B_ * T_;                     // 4096
  dim3 ggrid(C_ / 64, M / 64);
  dim3 gblk(256);

  gemm_nt<<<ggrid, gblk, 0, stream>>>(xq, Wq, M, C_, C_, nullptr, nullptr, Qh, Ql, 1);
  gemm_nt<<<ggrid, gblk, 0, stream>>>(xk, Wk, M, C_, C_, nullptr, nullptr, Kh, Kl, 1);
  gemm_nt<<<ggrid, gblk, 0, stream>>>(xv, Wv, M, C_, C_, nullptr, nullptr, Vh, nullptr, 0);

  dim3 agrid(B_ * (T_ / 16));                // 256 blocks
  attn_mfma<<<agrid, gblk, 0, stream>>>(Qh, Ql, Kh, Kl, Vh, AO);

  gemm_nt<<<ggrid, gblk, 0, stream>>>(AO, Wo, M, C_, C_, out, bo, nullptr, nullptr, 2);
}

// Round 4
// 1122.879 us; speedup vs baseline: 2.4379x; 1.3461x over previous
//
#include <hip/hip_runtime.h>
#include <cmath>

namespace {

constexpr int B_ = 2;
constexpr int T_ = 2048;
constexpr int C_ = 1024;
constexpr int H_ = 16;
constexpr int D_ = 64;

typedef _Float16 half8 __attribute__((ext_vector_type(8)));
typedef _Float16 half4 __attribute__((ext_vector_type(4)));
typedef float f32x4 __attribute__((ext_vector_type(4)));

__device__ inline f32x4 vmax4(f32x4 a, f32x4 b) {
  f32x4 r;
  r[0] = fmaxf(a[0], b[0]); r[1] = fmaxf(a[1], b[1]);
  r[2] = fmaxf(a[2], b[2]); r[3] = fmaxf(a[3], b[3]);
  return r;
}

// ---------------------------------------------------------------------------
// Y[m][n] = sum_k A[m][k] * W[n][k]; epilogue modes:
//   0: write f16 (Yh)            [V projection]
//   1: write f16 hi+lo (Yh, Yl)  [Q, K projections — Markidis split]
//   2: write fp32 + bias (Yf)    [output projection]
// ---------------------------------------------------------------------------
__global__ __launch_bounds__(256)
void gemm_nt(const float* __restrict__ A, const float* __restrict__ W,
             int M, int N, int K,
             float* __restrict__ Yf, const float* __restrict__ bias,
             _Float16* __restrict__ Yh, _Float16* __restrict__ Yl, int mode) {
  constexpr int BM = 64, BN = 64, BK = 16;
  __shared__ float As[BK][BM];
  __shared__ float Ws[BK][BN];

  const int tid = threadIdx.x;
  const int mbase = blockIdx.y * BM;
  const int nbase = blockIdx.x * BN;
  const int tx = tid & 15;
  const int ty = tid >> 4;
  const int lm = tid >> 2;
  const int lk = (tid & 3) * 4;

  const float* Ap = A + (size_t)(mbase + lm) * K + lk;
  const float* Wp = W + (size_t)(nbase + lm) * K + lk;

  float acc[4][4] = {};

  for (int k0 = 0; k0 < K; k0 += BK) {
    const float4 av = *(const float4*)(Ap + k0);
    const float4 wv = *(const float4*)(Wp + k0);
    __syncthreads();
    As[lk + 0][lm] = av.x; As[lk + 1][lm] = av.y;
    As[lk + 2][lm] = av.z; As[lk + 3][lm] = av.w;
    Ws[lk + 0][lm] = wv.x; Ws[lk + 1][lm] = wv.y;
    Ws[lk + 2][lm] = wv.z; Ws[lk + 3][lm] = wv.w;
    __syncthreads();
#pragma unroll
    for (int k = 0; k < BK; ++k) {
      const float4 a4 = *(const float4*)&As[k][ty * 4];
      const float4 b4 = *(const float4*)&Ws[k][tx * 4];
      const float a[4] = {a4.x, a4.y, a4.z, a4.w};
      const float b[4] = {b4.x, b4.y, b4.z, b4.w};
#pragma unroll
      for (int i = 0; i < 4; ++i)
#pragma unroll
        for (int j = 0; j < 4; ++j)
          acc[i][j] += a[i] * b[j];
    }
  }

  const int m0 = mbase + ty * 4;
  const int n0 = nbase + tx * 4;
#pragma unroll
  for (int i = 0; i < 4; ++i) {
    if (mode == 2) {
      float4 v;
      v.x = acc[i][0] + bias[n0 + 0];
      v.y = acc[i][1] + bias[n0 + 1];
      v.z = acc[i][2] + bias[n0 + 2];
      v.w = acc[i][3] + bias[n0 + 3];
      *(float4*)(Yf + (size_t)(m0 + i) * N + n0) = v;
    } else {
      half4 hi, lo;
#pragma unroll
      for (int j = 0; j < 4; ++j) {
        const float a = acc[i][j];
        const _Float16 h = (_Float16)a;
        hi[j] = h;
        lo[j] = (_Float16)(a - (float)h);
      }
      *(half4*)(Yh + (size_t)(m0 + i) * N + n0) = hi;
      if (mode == 1) *(half4*)(Yl + (size_t)(m0 + i) * N + n0) = lo;
    }
  }
}

// ---------------------------------------------------------------------------
// V pretranspose: Vh[b][t][c] -> Vt[b][h][kt][d][k16]  (f16, 8 MB)
// Block per (b, kt): 16 t-rows x 1024 c through a padded LDS tile.
// ---------------------------------------------------------------------------
__global__ __launch_bounds__(256)
void transpose_v(const _Float16* __restrict__ Vh, _Float16* __restrict__ Vt) {
  constexpr int PAD = 1028;  // halfs per LDS row
  __shared__ _Float16 tile[16][PAD];
  const int b  = blockIdx.x >> 7;
  const int kt = blockIdx.x & 127;
  const int tid = threadIdx.x;

#pragma unroll
  for (int j = 0; j < 8; ++j) {
    const int ch = tid + 256 * j;        // 0..2047
    const int t  = ch >> 7;
    const int c8 = ch & 127;
    *(half8*)&tile[t][c8 * 8] =
        *(const half8*)(Vh + ((size_t)b * T_ + kt * 16 + t) * C_ + c8 * 8);
  }
  __syncthreads();

#pragma unroll
  for (int j = 0; j < 8; ++j) {
    const int cc = tid + 256 * j;        // 0..2047
    const int h  = cc >> 7;
    const int d  = (cc >> 1) & 63;
    const int th = (cc & 1) * 8;
    half8 v;
#pragma unroll
    for (int i = 0; i < 8; ++i) v[i] = tile[th + i][h * 64 + d];
    *(half8*)(Vt + ((((size_t)b * H_ + h) * 128 + kt) * 64 + d) * 16 + th) = v;
  }
}

// ---------------------------------------------------------------------------
// MFMA attention, softmax over the HEAD axis.
// Block = (b, 16 q rows, k-split); 4 waves, wave w owns heads 4w..4w+3.
// S^T = K Q^T  (mfma_f32_16x16x32_f16, Markidis 3-product): C-layout of S^T
// (lane=q, reg=key) IS the B-fragment layout for PV -> probabilities go
// f32->f16 in-register, no LDS round-trip. V^T fragments load coalesced from
// the pretransposed Vt. LDS = 8 KB max/sum exchange only (conflict-free b128).
// Split-k partials are fp32, reduced by reduce_o (no atomics).
// ---------------------------------------------------------------------------
__global__ __launch_bounds__(256, 3)
void attn_mfma(const _Float16* __restrict__ Qhp, const _Float16* __restrict__ Qlp,
               const _Float16* __restrict__ Khp, const _Float16* __restrict__ Klp,
               const _Float16* __restrict__ Vtp, float* __restrict__ OP,
               int nsplit) {
  __shared__ f32x4 red[2][4][64];   // [max/sum][wave][cell]

  const int tid  = threadIdx.x;
  const int lane = tid & 63;
  const int w    = tid >> 6;
  const int l15  = lane & 15;
  const int quad = lane >> 4;
  const int cell = quad * 16 + l15;

  const int nbq   = B_ * (T_ / 16);
  const int split = blockIdx.x / nbq;
  const int bq    = blockIdx.x % nbq;
  const int b  = bq >> 7;
  const int q0 = (bq & 127) << 4;

  const size_t qrow = ((size_t)b * T_ + q0 + l15) * C_;

  f32x4 oacc[4][4];
#pragma unroll
  for (int hl = 0; hl < 4; ++hl)
#pragma unroll
    for (int mt = 0; mt < 4; ++mt)
      oacc[hl][mt] = (f32x4){0.f, 0.f, 0.f, 0.f};

  const int kpb  = T_ / nsplit;
  const int k_lo = split * kpb;

  for (int k0 = k_lo; k0 < k_lo + kpb; k0 += 16) {
    // ---- S^T = K Q^T (Markidis 3-product), scaled by sqrt(D)=8 quirk ----
    const size_t krow = ((size_t)b * T_ + k0 + l15) * C_;
    f32x4 s[4];
#pragma unroll
    for (int hl = 0; hl < 4; ++hl) s[hl] = (f32x4){0.f, 0.f, 0.f, 0.f};
#pragma unroll
    for (int hl = 0; hl < 4; ++hl)
#pragma unroll
      for (int kk = 0; kk < 2; ++kk) {
        const int off = (w * 4 + hl) * 64 + kk * 32 + quad * 8;
        const half8 kh = *(const half8*)(Khp + krow + off);
        const half8 kl = *(const half8*)(Klp + krow + off);
        const half8 qh = *(const half8*)(Qhp + qrow + off);
        const half8 ql = *(const half8*)(Qlp + qrow + off);
        s[hl] = __builtin_amdgcn_mfma_f32_16x16x32_f16(kh, qh, s[hl], 0, 0, 0);
        s[hl] = __builtin_amdgcn_mfma_f32_16x16x32_f16(kl, qh, s[hl], 0, 0, 0);
        s[hl] = __builtin_amdgcn_mfma_f32_16x16x32_f16(kh, ql, s[hl], 0, 0, 0);
      }
#pragma unroll
    for (int hl = 0; hl < 4; ++hl) s[hl] = s[hl] * 8.f;

    // ---- head-softmax: cross-wave max/sum via conflict-free b128 cells ----
    f32x4 pm = vmax4(vmax4(s[0], s[1]), vmax4(s[2], s[3]));
    __syncthreads();                 // red[] free from previous tile
    red[0][w][cell] = pm;
    __syncthreads();
    const f32x4 gmax = vmax4(vmax4(red[0][0][cell], red[0][1][cell]),
                             vmax4(red[0][2][cell], red[0][3][cell]));
    float e[4][4];
    f32x4 ps = (f32x4){0.f, 0.f, 0.f, 0.f};
#pragma unroll
    for (int hl = 0; hl < 4; ++hl)
#pragma unroll
      for (int r = 0; r < 4; ++r) {
        e[hl][r] = __expf(s[hl][r] - gmax[r]);
        ps[r] += e[hl][r];
      }
    red[1][w][cell] = ps;
    __syncthreads();
    const f32x4 gs = red[1][0][cell] + red[1][1][cell] +
                     red[1][2][cell] + red[1][3][cell];
    f32x4 inv;
#pragma unroll
    for (int r = 0; r < 4; ++r) inv[r] = 1.f / gs[r];

    // probabilities straight into B-fragment registers (no LDS!)
    half4 p[4];
#pragma unroll
    for (int hl = 0; hl < 4; ++hl)
#pragma unroll
      for (int r = 0; r < 4; ++r)
        p[hl][r] = (_Float16)(e[hl][r] * inv[r]);

    // ---- O^T += V^T P^T, V^T fragments coalesced from Vt ----
    const int kt = k0 >> 4;
#pragma unroll
    for (int hl = 0; hl < 4; ++hl) {
      const _Float16* vb =
          Vtp + (((size_t)b * H_ + (w * 4 + hl)) * 128 + kt) * 1024;
#pragma unroll
      for (int mt = 0; mt < 4; ++mt) {
        const half4 vf = *(const half4*)(vb + (mt * 16 + l15) * 16 + quad * 4);
        oacc[hl][mt] =
            __builtin_amdgcn_mfma_f32_16x16x16f16(vf, p[hl], oacc[hl][mt], 0, 0, 0);
      }
    }
  }

  // O^T C-layout: lane l15 = q; rows d = mt*16 + quad*4 + r (f32x4 contiguous)
  float* op = OP + (size_t)split * (B_ * T_ * C_);
  const size_t orow = ((size_t)b * T_ + q0 + l15) * C_;
#pragma unroll
  for (int hl = 0; hl < 4; ++hl)
#pragma unroll
    for (int mt = 0; mt < 4; ++mt) {
      float4 v;
      v.x = oacc[hl][mt][0]; v.y = oacc[hl][mt][1];
      v.z = oacc[hl][mt][2]; v.w = oacc[hl][mt][3];
      *(float4*)(op + orow + (w * 4 + hl) * 64 + mt * 16 + quad * 4) = v;
    }
}

// ---------------------------------------------------------------------------
// AO = sum over splits of OP[s]  (fp32, float4 per thread)
// ---------------------------------------------------------------------------
__global__ __launch_bounds__(256)
void reduce_o(const float* __restrict__ OP, float* __restrict__ AO,
              int nsplit, int n) {
  const int i = (blockIdx.x * 256 + threadIdx.x) * 4;
  float4 a = *(const float4*)(OP + i);
  for (int s = 1; s < nsplit; ++s) {
    const float4 b = *(const float4*)(OP + (size_t)s * n + i);
    a.x += b.x; a.y += b.y; a.z += b.z; a.w += b.w;
  }
  *(float4*)(AO + i) = a;
}

}  // namespace

extern "C" void kernel_launch(void* const* d_in, const int* in_sizes, int n_in,
                              void* d_out, int out_size, void* d_ws, size_t ws_size,
                              hipStream_t stream) {
  const float* xq = (const float*)d_in[0];
  const float* xk = (const float*)d_in[1];
  const float* xv = (const float*)d_in[2];
  const float* Wq = (const float*)d_in[3];
  const float* Wk = (const float*)d_in[4];
  const float* Wv = (const float*)d_in[5];
  const float* Wo = (const float*)d_in[6];
  const float* Wbias = (const float*)d_in[7];
  float* out = (float*)d_out;

  const size_t MB   = 1u << 20;
  const size_t nBTC = (size_t)B_ * T_ * C_;  // 4M elements

  // workspace layout (f16 slabs are 8 MB each):
  // [0..8) Qh  [8..16) Ql  [16..24) Kh  [24..32) Kl  [32..40) Vt
  // [40..48) Vh (dead after transpose)  [48..) OP fp32 partials
  // AO: nsplit>1 -> aliases [0..16) (Qh/Ql dead); nsplit==1 -> OP slab itself.
  char* wsb = (char*)d_ws;
  _Float16* Qh = (_Float16*)(wsb + 0 * MB);
  _Float16* Ql = (_Float16*)(wsb + 8 * MB);
  _Float16* Kh = (_Float16*)(wsb + 16 * MB);
  _Float16* Kl = (_Float16*)(wsb + 24 * MB);
  _Float16* Vt = (_Float16*)(wsb + 32 * MB);
  _Float16* Vh = (_Float16*)(wsb + 40 * MB);
  float*    OP = (float*)(wsb + 48 * MB);

  const int nsplit = (ws_size >= 113 * MB) ? 4 : (ws_size >= 81 * MB) ? 2 : 1;
  float* AO = (nsplit > 1) ? (float*)wsb : OP;

  const int M = B_ * T_;                     // 4096
  dim3 ggrid(C_ / 64, M / 64);
  dim3 gblk(256);

  gemm_nt<<<ggrid, gblk, 0, stream>>>(xq, Wq, M, C_, C_, nullptr, nullptr, Qh, Ql, 1);
  gemm_nt<<<ggrid, gblk, 0, stream>>>(xk, Wk, M, C_, C_, nullptr, nullptr, Kh, Kl, 1);
  gemm_nt<<<ggrid, gblk, 0, stream>>>(xv, Wv, M, C_, C_, nullptr, nullptr, Vh, nullptr, 0);

  transpose_v<<<dim3(B_ * 128), gblk, 0, stream>>>(Vh, Vt);

  dim3 agrid(B_ * (T_ / 16) * nsplit);
  attn_mfma<<<agrid, gblk, 0, stream>>>(Qh, Ql, Kh, Kl, Vt, OP, nsplit);

  if (nsplit > 1)
    reduce_o<<<dim3((int)(nBTC / 1024)), gblk, 0, stream>>>(OP, AO, nsplit, (int)nBTC);

  gemm_nt<<<ggrid, gblk, 0, stream>>>(AO, Wo, M, C_, C_, out, Wbias, nullptr, nullptr, 2);
}

// Round 5
// 872.755 us; speedup vs baseline: 3.1366x; 1.2866x over previous
//
#include <hip/hip_runtime.h>
#include <cmath>

namespace {

constexpr int B_ = 2;
constexpr int T_ = 2048;
constexpr int C_ = 1024;
constexpr int H_ = 16;
constexpr int D_ = 64;

typedef _Float16 half8 __attribute__((ext_vector_type(8)));
typedef _Float16 half4 __attribute__((ext_vector_type(4)));
typedef float f32x4 __attribute__((ext_vector_type(4)));

__device__ inline f32x4 vmax4(f32x4 a, f32x4 b) {
  f32x4 r;
  r[0] = fmaxf(a[0], b[0]); r[1] = fmaxf(a[1], b[1]);
  r[2] = fmaxf(a[2], b[2]); r[3] = fmaxf(a[3], b[3]);
  return r;
}

// ---------------------------------------------------------------------------
// fp32 -> f16 hi + f16 lo (Markidis split), two source arrays in one launch.
// ---------------------------------------------------------------------------
__global__ __launch_bounds__(256)
void cast_split2(const float* __restrict__ X, _Float16* __restrict__ Xh,
                 _Float16* __restrict__ Xl, int nX,
                 const float* __restrict__ W, _Float16* __restrict__ Wh,
                 _Float16* __restrict__ Wl, int nW) {
  const int i = (blockIdx.x * 256 + threadIdx.x) * 4;
  const float* s;
  _Float16 *ph, *pl;
  if (i < nX) { s = X + i; ph = Xh + i; pl = Xl + i; }
  else {
    const int j = i - nX;
    if (j >= nW) return;
    s = W + j; ph = Wh + j; pl = Wl + j;
  }
  const float4 v = *(const float4*)s;
  const float vv[4] = {v.x, v.y, v.z, v.w};
  half4 hi, lo;
#pragma unroll
  for (int r = 0; r < 4; ++r) {
    hi[r] = (_Float16)vv[r];
    lo[r] = (_Float16)(vv[r] - (float)hi[r]);
  }
  *(half4*)ph = hi;
  *(half4*)pl = lo;
}

// fp32 -> f16 (hi only), two source arrays in one launch.
__global__ __launch_bounds__(256)
void cast_plain2(const float* __restrict__ X, _Float16* __restrict__ Xh, int nX,
                 const float* __restrict__ W, _Float16* __restrict__ Wh, int nW) {
  const int i = (blockIdx.x * 256 + threadIdx.x) * 4;
  const float* s;
  _Float16* ph;
  if (i < nX) { s = X + i; ph = Xh + i; }
  else {
    const int j = i - nX;
    if (j >= nW) return;
    s = W + j; ph = Wh + j;
  }
  const float4 v = *(const float4*)s;
  const float vv[4] = {v.x, v.y, v.z, v.w};
  half4 hi;
#pragma unroll
  for (int r = 0; r < 4; ++r) hi[r] = (_Float16)vv[r];
  *(half4*)ph = hi;
}

// ---------------------------------------------------------------------------
// MFMA NT GEMM: Y[m][n] = sum_k A[m][k] * W[n][k]  (+bias).
// f16 inputs; markidis=1 adds lo-parts (3-product, fp32-grade result).
// Wave = 32(M) x 64(N) tile; block = 4 waves = 64 x 128; grid (N/128, M/64).
// Fragments load straight from global (rows are K-contiguous: half8 = 16B).
// C-regs hold Y^T-layout (lane l15 = m; quad*4+reg = n) -> coalesced stores.
// Epilogue modes: 0 = f16 Yh; 1 = f16 hi+lo (Yh,Yl); 2 = fp32 Yf + bias.
// ---------------------------------------------------------------------------
__global__ __launch_bounds__(256)
void mfma_gemm(const _Float16* __restrict__ Ah, const _Float16* __restrict__ Al,
               const _Float16* __restrict__ Wh, const _Float16* __restrict__ Wl,
               int M, int N, int K, int markidis,
               float* __restrict__ Yf, const float* __restrict__ bias,
               _Float16* __restrict__ Yh, _Float16* __restrict__ Yl, int mode) {
  const int tid  = threadIdx.x;
  const int lane = tid & 63;
  const int w    = tid >> 6;
  const int l15  = lane & 15;
  const int quad = lane >> 4;
  const int m0 = blockIdx.y * 64 + (w >> 1) * 32;
  const int n0 = blockIdx.x * 128 + (w & 1) * 64;

  const _Float16* a0h = Ah + (size_t)(m0 + l15) * K + quad * 8;
  const _Float16* w0h = Wh + (size_t)(n0 + l15) * K + quad * 8;
  const _Float16* a0l = markidis ? Al + (size_t)(m0 + l15) * K + quad * 8 : a0h;
  const _Float16* w0l = markidis ? Wl + (size_t)(n0 + l15) * K + quad * 8 : w0h;

  f32x4 acc[2][4];
#pragma unroll
  for (int mt = 0; mt < 2; ++mt)
#pragma unroll
    for (int nt = 0; nt < 4; ++nt)
      acc[mt][nt] = (f32x4){0.f, 0.f, 0.f, 0.f};

#pragma unroll 2
  for (int k0 = 0; k0 < K; k0 += 32) {
    half8 vh[2], uh[4], vl[2], ul[4];
#pragma unroll
    for (int mt = 0; mt < 2; ++mt)
      vh[mt] = *(const half8*)(a0h + (size_t)mt * 16 * K + k0);
#pragma unroll
    for (int nt = 0; nt < 4; ++nt)
      uh[nt] = *(const half8*)(w0h + (size_t)nt * 16 * K + k0);
    if (markidis) {
#pragma unroll
      for (int mt = 0; mt < 2; ++mt)
        vl[mt] = *(const half8*)(a0l + (size_t)mt * 16 * K + k0);
#pragma unroll
      for (int nt = 0; nt < 4; ++nt)
        ul[nt] = *(const half8*)(w0l + (size_t)nt * 16 * K + k0);
    }
#pragma unroll
    for (int mt = 0; mt < 2; ++mt)
#pragma unroll
      for (int nt = 0; nt < 4; ++nt) {
        acc[mt][nt] = __builtin_amdgcn_mfma_f32_16x16x32_f16(uh[nt], vh[mt], acc[mt][nt], 0, 0, 0);
        if (markidis) {
          acc[mt][nt] = __builtin_amdgcn_mfma_f32_16x16x32_f16(ul[nt], vh[mt], acc[mt][nt], 0, 0, 0);
          acc[mt][nt] = __builtin_amdgcn_mfma_f32_16x16x32_f16(uh[nt], vl[mt], acc[mt][nt], 0, 0, 0);
        }
      }
  }

#pragma unroll
  for (int mt = 0; mt < 2; ++mt)
#pragma unroll
    for (int nt = 0; nt < 4; ++nt) {
      const int m = m0 + mt * 16 + l15;
      const int n = n0 + nt * 16 + quad * 4;
      if (mode == 2) {
        float4 v;
        v.x = acc[mt][nt][0] + bias[n + 0];
        v.y = acc[mt][nt][1] + bias[n + 1];
        v.z = acc[mt][nt][2] + bias[n + 2];
        v.w = acc[mt][nt][3] + bias[n + 3];
        *(float4*)(Yf + (size_t)m * N + n) = v;
      } else {
        half4 hi;
#pragma unroll
        for (int r = 0; r < 4; ++r) hi[r] = (_Float16)acc[mt][nt][r];
        *(half4*)(Yh + (size_t)m * N + n) = hi;
        if (mode == 1) {
          half4 lo;
#pragma unroll
          for (int r = 0; r < 4; ++r)
            lo[r] = (_Float16)(acc[mt][nt][r] - (float)hi[r]);
          *(half4*)(Yl + (size_t)m * N + n) = lo;
        }
      }
    }
}

// ---------------------------------------------------------------------------
// V pretranspose: Vh[b][t][c] -> Vt[b][h][kt][d][k16]  (f16, 8 MB)
// ---------------------------------------------------------------------------
__global__ __launch_bounds__(256)
void transpose_v(const _Float16* __restrict__ Vh, _Float16* __restrict__ Vt) {
  constexpr int PAD = 1028;
  __shared__ _Float16 tile[16][PAD];
  const int b  = blockIdx.x >> 7;
  const int kt = blockIdx.x & 127;
  const int tid = threadIdx.x;

#pragma unroll
  for (int j = 0; j < 8; ++j) {
    const int ch = tid + 256 * j;
    const int t  = ch >> 7;
    const int c8 = ch & 127;
    *(half8*)&tile[t][c8 * 8] =
        *(const half8*)(Vh + ((size_t)b * T_ + kt * 16 + t) * C_ + c8 * 8);
  }
  __syncthreads();

#pragma unroll
  for (int j = 0; j < 8; ++j) {
    const int cc = tid + 256 * j;
    const int h  = cc >> 7;
    const int d  = (cc >> 1) & 63;
    const int th = (cc & 1) * 8;
    half8 v;
#pragma unroll
    for (int i = 0; i < 8; ++i) v[i] = tile[th + i][h * 64 + d];
    *(half8*)(Vt + ((((size_t)b * H_ + h) * 128 + kt) * 64 + d) * 16 + th) = v;
  }
}

// ---------------------------------------------------------------------------
// MFMA attention, softmax over the HEAD axis (see R4 notes).
// Split-k partials stored f16 (|O| ~ O(10) -> abs err ~1e-2, harmless).
// ---------------------------------------------------------------------------
__global__ __launch_bounds__(256, 3)
void attn_mfma(const _Float16* __restrict__ Qhp, const _Float16* __restrict__ Qlp,
               const _Float16* __restrict__ Khp, const _Float16* __restrict__ Klp,
               const _Float16* __restrict__ Vtp, _Float16* __restrict__ OP,
               int nsplit) {
  __shared__ f32x4 red[2][4][64];

  const int tid  = threadIdx.x;
  const int lane = tid & 63;
  const int w    = tid >> 6;
  const int l15  = lane & 15;
  const int quad = lane >> 4;
  const int cell = quad * 16 + l15;

  const int nbq   = B_ * (T_ / 16);
  const int split = blockIdx.x / nbq;
  const int bq    = blockIdx.x % nbq;
  const int b  = bq >> 7;
  const int q0 = (bq & 127) << 4;

  const size_t qrow = ((size_t)b * T_ + q0 + l15) * C_;

  f32x4 oacc[4][4];
#pragma unroll
  for (int hl = 0; hl < 4; ++hl)
#pragma unroll
    for (int mt = 0; mt < 4; ++mt)
      oacc[hl][mt] = (f32x4){0.f, 0.f, 0.f, 0.f};

  const int kpb  = T_ / nsplit;
  const int k_lo = split * kpb;

  for (int k0 = k_lo; k0 < k_lo + kpb; k0 += 16) {
    // ---- S^T = K Q^T (Markidis 3-product), * sqrt(D)=8 quirk ----
    const size_t krow = ((size_t)b * T_ + k0 + l15) * C_;
    f32x4 s[4];
#pragma unroll
    for (int hl = 0; hl < 4; ++hl) s[hl] = (f32x4){0.f, 0.f, 0.f, 0.f};
#pragma unroll
    for (int hl = 0; hl < 4; ++hl)
#pragma unroll
      for (int kk = 0; kk < 2; ++kk) {
        const int off = (w * 4 + hl) * 64 + kk * 32 + quad * 8;
        const half8 kh = *(const half8*)(Khp + krow + off);
        const half8 kl = *(const half8*)(Klp + krow + off);
        const half8 qh = *(const half8*)(Qhp + qrow + off);
        const half8 ql = *(const half8*)(Qlp + qrow + off);
        s[hl] = __builtin_amdgcn_mfma_f32_16x16x32_f16(kh, qh, s[hl], 0, 0, 0);
        s[hl] = __builtin_amdgcn_mfma_f32_16x16x32_f16(kl, qh, s[hl], 0, 0, 0);
        s[hl] = __builtin_amdgcn_mfma_f32_16x16x32_f16(kh, ql, s[hl], 0, 0, 0);
      }
#pragma unroll
    for (int hl = 0; hl < 4; ++hl) s[hl] = s[hl] * 8.f;

    // ---- head-softmax via cross-wave LDS max/sum ----
    f32x4 pm = vmax4(vmax4(s[0], s[1]), vmax4(s[2], s[3]));
    __syncthreads();
    red[0][w][cell] = pm;
    __syncthreads();
    const f32x4 gmax = vmax4(vmax4(red[0][0][cell], red[0][1][cell]),
                             vmax4(red[0][2][cell], red[0][3][cell]));
    float e[4][4];
    f32x4 ps = (f32x4){0.f, 0.f, 0.f, 0.f};
#pragma unroll
    for (int hl = 0; hl < 4; ++hl)
#pragma unroll
      for (int r = 0; r < 4; ++r) {
        e[hl][r] = __expf(s[hl][r] - gmax[r]);
        ps[r] += e[hl][r];
      }
    red[1][w][cell] = ps;
    __syncthreads();
    const f32x4 gs = red[1][0][cell] + red[1][1][cell] +
                     red[1][2][cell] + red[1][3][cell];
    f32x4 inv;
#pragma unroll
    for (int r = 0; r < 4; ++r) inv[r] = 1.f / gs[r];

    half4 p[4];
#pragma unroll
    for (int hl = 0; hl < 4; ++hl)
#pragma unroll
      for (int r = 0; r < 4; ++r)
        p[hl][r] = (_Float16)(e[hl][r] * inv[r]);

    // ---- O^T += V^T P^T ----
    const int kt = k0 >> 4;
#pragma unroll
    for (int hl = 0; hl < 4; ++hl) {
      const _Float16* vb =
          Vtp + (((size_t)b * H_ + (w * 4 + hl)) * 128 + kt) * 1024;
#pragma unroll
      for (int mt = 0; mt < 4; ++mt) {
        const half4 vf = *(const half4*)(vb + (mt * 16 + l15) * 16 + quad * 4);
        oacc[hl][mt] =
            __builtin_amdgcn_mfma_f32_16x16x16f16(vf, p[hl], oacc[hl][mt], 0, 0, 0);
      }
    }
  }

  _Float16* op = OP + (size_t)split * ((size_t)B_ * T_ * C_);
  const size_t orow = ((size_t)b * T_ + q0 + l15) * C_;
#pragma unroll
  for (int hl = 0; hl < 4; ++hl)
#pragma unroll
    for (int mt = 0; mt < 4; ++mt) {
      half4 hv;
#pragma unroll
      for (int r = 0; r < 4; ++r) hv[r] = (_Float16)oacc[hl][mt][r];
      *(half4*)(op + orow + (w * 4 + hl) * 64 + mt * 16 + quad * 4) = hv;
    }
}

// ---------------------------------------------------------------------------
// AO = sum over splits of f16 OP[s]  (fp32 accumulate, fp32 out)
// ---------------------------------------------------------------------------
__global__ __launch_bounds__(256)
void reduce_o(const _Float16* __restrict__ OP, float* __restrict__ AO,
              int nsplit, size_t n) {
  const size_t i = ((size_t)blockIdx.x * 256 + threadIdx.x) * 4;
  float4 a = {0.f, 0.f, 0.f, 0.f};
  for (int s = 0; s < nsplit; ++s) {
    const half4 v = *(const half4*)(OP + (size_t)s * n + i);
    a.x += (float)v[0]; a.y += (float)v[1];
    a.z += (float)v[2]; a.w += (float)v[3];
  }
  *(float4*)(AO + i) = a;
}

}  // namespace

extern "C" void kernel_launch(void* const* d_in, const int* in_sizes, int n_in,
                              void* d_out, int out_size, void* d_ws, size_t ws_size,
                              hipStream_t stream) {
  const float* xq = (const float*)d_in[0];
  const float* xk = (const float*)d_in[1];
  const float* xv = (const float*)d_in[2];
  const float* Wq = (const float*)d_in[3];
  const float* Wk = (const float*)d_in[4];
  const float* Wv = (const float*)d_in[5];
  const float* Wo = (const float*)d_in[6];
  const float* bo = (const float*)d_in[7];
  float* out = (float*)d_out;

  const size_t MB   = 1ull << 20;
  const size_t nBTC = (size_t)B_ * T_ * C_;  // 4M elements
  const int    nW   = C_ * C_;               // 1M elements

  // workspace layout (MB):
  //  [0,8) Qh   [8,16) Ql   [16,24) Kh   [24,32) Kl   [32,40) Vt
  //  [40,48) XSh  [48,56) XSl  [56,64) VhTmp  [64,68) WWh  [68,72) WWl
  //  attn-time:  OP f16 partials at [40, 40+8*nsplit)   (XS/Vh/WW dead)
  //  post-attn:  AO fp32 [0,16)  AOh [16,24)  Woh [32,36)
  char* wsb = (char*)d_ws;
  _Float16* Qh  = (_Float16*)(wsb + 0 * MB);
  _Float16* Ql  = (_Float16*)(wsb + 8 * MB);
  _Float16* Kh  = (_Float16*)(wsb + 16 * MB);
  _Float16* Kl  = (_Float16*)(wsb + 24 * MB);
  _Float16* Vt  = (_Float16*)(wsb + 32 * MB);
  _Float16* XSh = (_Float16*)(wsb + 40 * MB);
  _Float16* XSl = (_Float16*)(wsb + 48 * MB);
  _Float16* VhT = (_Float16*)(wsb + 56 * MB);
  _Float16* WWh = (_Float16*)(wsb + 64 * MB);
  _Float16* WWl = (_Float16*)(wsb + 68 * MB);
  _Float16* OP  = (_Float16*)(wsb + 40 * MB);
  float*    AO  = (float*)(wsb + 0 * MB);
  _Float16* AOh = (_Float16*)(wsb + 16 * MB);
  _Float16* Woh = (_Float16*)(wsb + 32 * MB);

  const int nsplit = (ws_size >= 104 * MB) ? 8 : 4;  // peak: 40+8n vs 72 MB

  const int M = B_ * T_;                     // 4096
  dim3 blk(256);
  dim3 cgrid((unsigned)((nBTC + nW) / 1024));
  dim3 ggrid(C_ / 128, M / 64);              // (8, 64) = 512 blocks

  // Q projection (Markidis)
  cast_split2<<<cgrid, blk, 0, stream>>>(xq, XSh, XSl, (int)nBTC, Wq, WWh, WWl, nW);
  mfma_gemm<<<ggrid, blk, 0, stream>>>(XSh, XSl, WWh, WWl, M, C_, C_, 1,
                                       nullptr, nullptr, Qh, Ql, 1);
  // K projection (Markidis)
  cast_split2<<<cgrid, blk, 0, stream>>>(xk, XSh, XSl, (int)nBTC, Wk, WWh, WWl, nW);
  mfma_gemm<<<ggrid, blk, 0, stream>>>(XSh, XSl, WWh, WWl, M, C_, C_, 1,
                                       nullptr, nullptr, Kh, Kl, 1);
  // V projection (plain f16)
  cast_plain2<<<cgrid, blk, 0, stream>>>(xv, XSh, (int)nBTC, Wv, WWh, nW);
  mfma_gemm<<<ggrid, blk, 0, stream>>>(XSh, nullptr, WWh, nullptr, M, C_, C_, 0,
                                       nullptr, nullptr, VhT, nullptr, 0);

  transpose_v<<<dim3(B_ * 128), blk, 0, stream>>>(VhT, Vt);

  dim3 agrid(B_ * (T_ / 16) * nsplit);
  attn_mfma<<<agrid, blk, 0, stream>>>(Qh, Ql, Kh, Kl, Vt, OP, nsplit);

  reduce_o<<<dim3((unsigned)(nBTC / 1024)), blk, 0, stream>>>(OP, AO, nsplit, nBTC);

  // output projection (plain f16) + bias
  cast_plain2<<<cgrid, blk, 0, stream>>>(AO, AOh, (int)nBTC, Wo, Woh, nW);
  mfma_gemm<<<ggrid, blk, 0, stream>>>(AOh, nullptr, Woh, nullptr, M, C_, C_, 0,
                                       out, bo, nullptr, nullptr, 2);
}

// Round 6
// 769.607 us; speedup vs baseline: 3.5570x; 1.1340x over previous
//
#include <hip/hip_runtime.h>
#include <cmath>

namespace {

constexpr int B_ = 2;
constexpr int T_ = 2048;
constexpr int C_ = 1024;
constexpr int H_ = 16;
constexpr int D_ = 64;

typedef _Float16 half8 __attribute__((ext_vector_type(8)));
typedef _Float16 half4 __attribute__((ext_vector_type(4)));
typedef float f32x4 __attribute__((ext_vector_type(4)));

__device__ inline f32x4 vmax4(f32x4 a, f32x4 b) {
  f32x4 r;
  r[0] = fmaxf(a[0], b[0]); r[1] = fmaxf(a[1], b[1]);
  r[2] = fmaxf(a[2], b[2]); r[3] = fmaxf(a[3], b[3]);
  return r;
}

// ---------------------------------------------------------------------------
// fp32 -> f16 hi + f16 lo (Markidis split), two source arrays in one launch.
// ---------------------------------------------------------------------------
__global__ __launch_bounds__(256)
void cast_split2(const float* __restrict__ X, _Float16* __restrict__ Xh,
                 _Float16* __restrict__ Xl, int nX,
                 const float* __restrict__ W, _Float16* __restrict__ Wh,
                 _Float16* __restrict__ Wl, int nW) {
  const int i = (blockIdx.x * 256 + threadIdx.x) * 4;
  const float* s;
  _Float16 *ph, *pl;
  if (i < nX) { s = X + i; ph = Xh + i; pl = Xl + i; }
  else {
    const int j = i - nX;
    if (j >= nW) return;
    s = W + j; ph = Wh + j; pl = Wl + j;
  }
  const float4 v = *(const float4*)s;
  const float vv[4] = {v.x, v.y, v.z, v.w};
  half4 hi, lo;
#pragma unroll
  for (int r = 0; r < 4; ++r) {
    hi[r] = (_Float16)vv[r];
    lo[r] = (_Float16)(vv[r] - (float)hi[r]);
  }
  *(half4*)ph = hi;
  *(half4*)pl = lo;
}

// fp32 -> f16 (hi only), two source arrays in one launch.
__global__ __launch_bounds__(256)
void cast_plain2(const float* __restrict__ X, _Float16* __restrict__ Xh, int nX,
                 const float* __restrict__ W, _Float16* __restrict__ Wh, int nW) {
  const int i = (blockIdx.x * 256 + threadIdx.x) * 4;
  const float* s;
  _Float16* ph;
  if (i < nX) { s = X + i; ph = Xh + i; }
  else {
    const int j = i - nX;
    if (j >= nW) return;
    s = W + j; ph = Wh + j;
  }
  const float4 v = *(const float4*)s;
  const float vv[4] = {v.x, v.y, v.z, v.w};
  half4 hi;
#pragma unroll
  for (int r = 0; r < 4; ++r) hi[r] = (_Float16)vv[r];
  *(half4*)ph = hi;
}

// ---------------------------------------------------------------------------
// MFMA NT GEMM (unchanged from R5): Y[m][n] = sum_k A[m][k]*W[n][k] (+bias).
// ---------------------------------------------------------------------------
__global__ __launch_bounds__(256)
void mfma_gemm(const _Float16* __restrict__ Ah, const _Float16* __restrict__ Al,
               const _Float16* __restrict__ Wh, const _Float16* __restrict__ Wl,
               int M, int N, int K, int markidis,
               float* __restrict__ Yf, const float* __restrict__ bias,
               _Float16* __restrict__ Yh, _Float16* __restrict__ Yl, int mode) {
  const int tid  = threadIdx.x;
  const int lane = tid & 63;
  const int w    = tid >> 6;
  const int l15  = lane & 15;
  const int quad = lane >> 4;
  const int m0 = blockIdx.y * 64 + (w >> 1) * 32;
  const int n0 = blockIdx.x * 128 + (w & 1) * 64;

  const _Float16* a0h = Ah + (size_t)(m0 + l15) * K + quad * 8;
  const _Float16* w0h = Wh + (size_t)(n0 + l15) * K + quad * 8;
  const _Float16* a0l = markidis ? Al + (size_t)(m0 + l15) * K + quad * 8 : a0h;
  const _Float16* w0l = markidis ? Wl + (size_t)(n0 + l15) * K + quad * 8 : w0h;

  f32x4 acc[2][4];
#pragma unroll
  for (int mt = 0; mt < 2; ++mt)
#pragma unroll
    for (int nt = 0; nt < 4; ++nt)
      acc[mt][nt] = (f32x4){0.f, 0.f, 0.f, 0.f};

#pragma unroll 2
  for (int k0 = 0; k0 < K; k0 += 32) {
    half8 vh[2], uh[4], vl[2], ul[4];
#pragma unroll
    for (int mt = 0; mt < 2; ++mt)
      vh[mt] = *(const half8*)(a0h + (size_t)mt * 16 * K + k0);
#pragma unroll
    for (int nt = 0; nt < 4; ++nt)
      uh[nt] = *(const half8*)(w0h + (size_t)nt * 16 * K + k0);
    if (markidis) {
#pragma unroll
      for (int mt = 0; mt < 2; ++mt)
        vl[mt] = *(const half8*)(a0l + (size_t)mt * 16 * K + k0);
#pragma unroll
      for (int nt = 0; nt < 4; ++nt)
        ul[nt] = *(const half8*)(w0l + (size_t)nt * 16 * K + k0);
    }
#pragma unroll
    for (int mt = 0; mt < 2; ++mt)
#pragma unroll
      for (int nt = 0; nt < 4; ++nt) {
        acc[mt][nt] = __builtin_amdgcn_mfma_f32_16x16x32_f16(uh[nt], vh[mt], acc[mt][nt], 0, 0, 0);
        if (markidis) {
          acc[mt][nt] = __builtin_amdgcn_mfma_f32_16x16x32_f16(ul[nt], vh[mt], acc[mt][nt], 0, 0, 0);
          acc[mt][nt] = __builtin_amdgcn_mfma_f32_16x16x32_f16(uh[nt], vl[mt], acc[mt][nt], 0, 0, 0);
        }
      }
  }

#pragma unroll
  for (int mt = 0; mt < 2; ++mt)
#pragma unroll
    for (int nt = 0; nt < 4; ++nt) {
      const int m = m0 + mt * 16 + l15;
      const int n = n0 + nt * 16 + quad * 4;
      if (mode == 2) {
        float4 v;
        v.x = acc[mt][nt][0] + bias[n + 0];
        v.y = acc[mt][nt][1] + bias[n + 1];
        v.z = acc[mt][nt][2] + bias[n + 2];
        v.w = acc[mt][nt][3] + bias[n + 3];
        *(float4*)(Yf + (size_t)m * N + n) = v;
      } else {
        half4 hi;
#pragma unroll
        for (int r = 0; r < 4; ++r) hi[r] = (_Float16)acc[mt][nt][r];
        *(half4*)(Yh + (size_t)m * N + n) = hi;
        if (mode == 1) {
          half4 lo;
#pragma unroll
          for (int r = 0; r < 4; ++r)
            lo[r] = (_Float16)(acc[mt][nt][r] - (float)hi[r]);
          *(half4*)(Yl + (size_t)m * N + n) = lo;
        }
      }
    }
}

// ---------------------------------------------------------------------------
// V pretranspose: Vh[b][t][c] -> Vt[b][h][kt][d][k16]  (f16, 8 MB)
// ---------------------------------------------------------------------------
__global__ __launch_bounds__(256)
void transpose_v(const _Float16* __restrict__ Vh, _Float16* __restrict__ Vt) {
  constexpr int PAD = 1028;
  __shared__ _Float16 tile[16][PAD];
  const int b  = blockIdx.x >> 7;
  const int kt = blockIdx.x & 127;
  const int tid = threadIdx.x;

#pragma unroll
  for (int j = 0; j < 8; ++j) {
    const int ch = tid + 256 * j;
    const int t  = ch >> 7;
    const int c8 = ch & 127;
    *(half8*)&tile[t][c8 * 8] =
        *(const half8*)(Vh + ((size_t)b * T_ + kt * 16 + t) * C_ + c8 * 8);
  }
  __syncthreads();

#pragma unroll
  for (int j = 0; j < 8; ++j) {
    const int cc = tid + 256 * j;
    const int h  = cc >> 7;
    const int d  = (cc >> 1) & 63;
    const int th = (cc & 1) * 8;
    half8 v;
#pragma unroll
    for (int i = 0; i < 8; ++i) v[i] = tile[th + i][h * 64 + d];
    *(half8*)(Vt + ((((size_t)b * H_ + h) * 128 + kt) * 64 + d) * 16 + th) = v;
  }
}

// ---------------------------------------------------------------------------
// MFMA head-softmax attention v3: batched per-tile loads (ILP over latency),
// ping-pong reduction LDS (2 barriers/tile). See R4/R5 notes for layout math.
// ---------------------------------------------------------------------------
__global__ __launch_bounds__(256, 2)
void attn_mfma(const _Float16* __restrict__ Qhp, const _Float16* __restrict__ Qlp,
               const _Float16* __restrict__ Khp, const _Float16* __restrict__ Klp,
               const _Float16* __restrict__ Vtp, _Float16* __restrict__ OP,
               int nsplit) {
  __shared__ f32x4 red[2][2][4][64];   // [phase][max|sum][wave][lane-cell] = 32 KB

  const int tid  = threadIdx.x;
  const int lane = tid & 63;
  const int w    = tid >> 6;
  const int l15  = lane & 15;
  const int quad = lane >> 4;
  const int cell = quad * 16 + l15;

  const int nbq   = B_ * (T_ / 16);
  const int split = blockIdx.x / nbq;
  const int bq    = blockIdx.x % nbq;
  const int b  = bq >> 7;
  const int q0 = (bq & 127) << 4;

  const size_t qrow = ((size_t)b * T_ + q0 + l15) * C_;

  f32x4 oacc[4][4];
#pragma unroll
  for (int hl = 0; hl < 4; ++hl)
#pragma unroll
    for (int mt = 0; mt < 4; ++mt)
      oacc[hl][mt] = (f32x4){0.f, 0.f, 0.f, 0.f};

  const int kpb  = T_ / nsplit;
  const int k_lo = split * kpb;
  const int jt   = kpb / 16;

  for (int j = 0; j < jt; ++j) {
    const int k0 = k_lo + j * 16;
    const int p  = j & 1;
    const int kt = k0 >> 4;
    const size_t krow = ((size_t)b * T_ + k0 + l15) * C_;

    // ---- batched loads: 24 K/Q half8 + 16 V half4 in flight together ----
    half8 akh[4][2], akl[4][2], aqh[4][2];
    half4 avf[4][4];
#pragma unroll
    for (int hl = 0; hl < 4; ++hl)
#pragma unroll
      for (int kk = 0; kk < 2; ++kk) {
        const int off = (w * 4 + hl) * 64 + kk * 32 + quad * 8;
        akh[hl][kk] = *(const half8*)(Khp + krow + off);
        akl[hl][kk] = *(const half8*)(Klp + krow + off);
        aqh[hl][kk] = *(const half8*)(Qhp + qrow + off);
      }
#pragma unroll
    for (int hl = 0; hl < 4; ++hl) {
      const _Float16* vb =
          Vtp + (((size_t)b * H_ + (w * 4 + hl)) * 128 + kt) * 1024;
#pragma unroll
      for (int mt = 0; mt < 4; ++mt)
        avf[hl][mt] = *(const half4*)(vb + (mt * 16 + l15) * 16 + quad * 4);
    }

    // ---- S^T = K Q^T (Markidis 3-product), * sqrt(D)=8 quirk ----
    f32x4 s[4];
#pragma unroll
    for (int hl = 0; hl < 4; ++hl) s[hl] = (f32x4){0.f, 0.f, 0.f, 0.f};
#pragma unroll
    for (int hl = 0; hl < 4; ++hl)
#pragma unroll
      for (int kk = 0; kk < 2; ++kk) {
        const int off = (w * 4 + hl) * 64 + kk * 32 + quad * 8;
        const half8 ql = *(const half8*)(Qlp + qrow + off);
        s[hl] = __builtin_amdgcn_mfma_f32_16x16x32_f16(akh[hl][kk], aqh[hl][kk], s[hl], 0, 0, 0);
        s[hl] = __builtin_amdgcn_mfma_f32_16x16x32_f16(akl[hl][kk], aqh[hl][kk], s[hl], 0, 0, 0);
        s[hl] = __builtin_amdgcn_mfma_f32_16x16x32_f16(akh[hl][kk], ql,          s[hl], 0, 0, 0);
      }
#pragma unroll
    for (int hl = 0; hl < 4; ++hl) s[hl] = s[hl] * 8.f;

    // ---- head-softmax, ping-pong LDS: 2 barriers/tile ----
    red[p][0][w][cell] = vmax4(vmax4(s[0], s[1]), vmax4(s[2], s[3]));
    __syncthreads();
    const f32x4 gmax = vmax4(vmax4(red[p][0][0][cell], red[p][0][1][cell]),
                             vmax4(red[p][0][2][cell], red[p][0][3][cell]));
    float e[4][4];
    f32x4 ps = (f32x4){0.f, 0.f, 0.f, 0.f};
#pragma unroll
    for (int hl = 0; hl < 4; ++hl)
#pragma unroll
      for (int r = 0; r < 4; ++r) {
        e[hl][r] = __expf(s[hl][r] - gmax[r]);
        ps[r] += e[hl][r];
      }
    red[p][1][w][cell] = ps;
    __syncthreads();
    const f32x4 gs = red[p][1][0][cell] + red[p][1][1][cell] +
                     red[p][1][2][cell] + red[p][1][3][cell];
    f32x4 inv;
#pragma unroll
    for (int r = 0; r < 4; ++r) inv[r] = 1.f / gs[r];

    half4 pf[4];
#pragma unroll
    for (int hl = 0; hl < 4; ++hl)
#pragma unroll
      for (int r = 0; r < 4; ++r)
        pf[hl][r] = (_Float16)(e[hl][r] * inv[r]);

    // ---- O^T += V^T P^T (V frags already resident) ----
#pragma unroll
    for (int hl = 0; hl < 4; ++hl)
#pragma unroll
      for (int mt = 0; mt < 4; ++mt)
        oacc[hl][mt] =
            __builtin_amdgcn_mfma_f32_16x16x16f16(avf[hl][mt], pf[hl], oacc[hl][mt], 0, 0, 0);
  }

  _Float16* op = OP + (size_t)split * ((size_t)B_ * T_ * C_);
  const size_t orow = ((size_t)b * T_ + q0 + l15) * C_;
#pragma unroll
  for (int hl = 0; hl < 4; ++hl)
#pragma unroll
    for (int mt = 0; mt < 4; ++mt) {
      half4 hv;
#pragma unroll
      for (int r = 0; r < 4; ++r) hv[r] = (_Float16)oacc[hl][mt][r];
      *(half4*)(op + orow + (w * 4 + hl) * 64 + mt * 16 + quad * 4) = hv;
    }
}

// ---------------------------------------------------------------------------
// AOh = (f16) sum over splits of f16 OP[s]  (fp32 accumulate) — fused cast.
// ---------------------------------------------------------------------------
__global__ __launch_bounds__(256)
void reduce_oh(const _Float16* __restrict__ OP, _Float16* __restrict__ AOh,
               int nsplit, size_t n) {
  const size_t i = ((size_t)blockIdx.x * 256 + threadIdx.x) * 8;
  float a[8] = {};
  for (int s = 0; s < nsplit; ++s) {
    const half8 v = *(const half8*)(OP + (size_t)s * n + i);
#pragma unroll
    for (int r = 0; r < 8; ++r) a[r] += (float)v[r];
  }
  half8 o;
#pragma unroll
  for (int r = 0; r < 8; ++r) o[r] = (_Float16)a[r];
  *(half8*)(AOh + i) = o;
}

}  // namespace

extern "C" void kernel_launch(void* const* d_in, const int* in_sizes, int n_in,
                              void* d_out, int out_size, void* d_ws, size_t ws_size,
                              hipStream_t stream) {
  const float* xq = (const float*)d_in[0];
  const float* xk = (const float*)d_in[1];
  const float* xv = (const float*)d_in[2];
  const float* Wq = (const float*)d_in[3];
  const float* Wk = (const float*)d_in[4];
  const float* Wv = (const float*)d_in[5];
  const float* Wo = (const float*)d_in[6];
  const float* bo = (const float*)d_in[7];
  float* out = (float*)d_out;

  const size_t MB   = 1ull << 20;
  const size_t nBTC = (size_t)B_ * T_ * C_;  // 4M elements
  const int    nW   = C_ * C_;               // 1M elements

  // workspace (MB):
  //  [0,8) Qh   [8,16) Ql   [16,24) Kh   [24,32) Kl   [32,40) Vt
  //  [40,48) XSh  [48,56) XSl  [56,64) VhTmp  [64,68) WWh  [68,72) WWl
  //  attn:      OP f16 partials [40, 40+8*nsplit)
  //  post-attn: AOh [0,8) (Qh dead)   Woh [72,74)
  char* wsb = (char*)d_ws;
  _Float16* Qh  = (_Float16*)(wsb + 0 * MB);
  _Float16* Ql  = (_Float16*)(wsb + 8 * MB);
  _Float16* Kh  = (_Float16*)(wsb + 16 * MB);
  _Float16* Kl  = (_Float16*)(wsb + 24 * MB);
  _Float16* Vt  = (_Float16*)(wsb + 32 * MB);
  _Float16* XSh = (_Float16*)(wsb + 40 * MB);
  _Float16* XSl = (_Float16*)(wsb + 48 * MB);
  _Float16* VhT = (_Float16*)(wsb + 56 * MB);
  _Float16* WWh = (_Float16*)(wsb + 64 * MB);
  _Float16* WWl = (_Float16*)(wsb + 68 * MB);
  _Float16* OP  = (_Float16*)(wsb + 40 * MB);
  _Float16* AOh = (_Float16*)(wsb + 0 * MB);
  _Float16* Woh = (_Float16*)(wsb + 72 * MB);

  const int nsplit = 4;                      // OP = 32 MB at [40,72): fits ws >= 81 MB

  const int M = B_ * T_;                     // 4096
  dim3 blk(256);
  dim3 cgrid((unsigned)((nBTC + nW) / 1024));
  dim3 ggrid(C_ / 128, M / 64);              // (8, 64) = 512 blocks

  // Q projection (Markidis)
  cast_split2<<<cgrid, blk, 0, stream>>>(xq, XSh, XSl, (int)nBTC, Wq, WWh, WWl, nW);
  mfma_gemm<<<ggrid, blk, 0, stream>>>(XSh, XSl, WWh, WWl, M, C_, C_, 1,
                                       nullptr, nullptr, Qh, Ql, 1);
  // K projection (Markidis)
  cast_split2<<<cgrid, blk, 0, stream>>>(xk, XSh, XSl, (int)nBTC, Wk, WWh, WWl, nW);
  mfma_gemm<<<ggrid, blk, 0, stream>>>(XSh, XSl, WWh, WWl, M, C_, C_, 1,
                                       nullptr, nullptr, Kh, Kl, 1);
  // V projection (plain f16)
  cast_plain2<<<cgrid, blk, 0, stream>>>(xv, XSh, (int)nBTC, Wv, WWh, nW);
  mfma_gemm<<<ggrid, blk, 0, stream>>>(XSh, nullptr, WWh, nullptr, M, C_, C_, 0,
                                       nullptr, nullptr, VhT, nullptr, 0);

  transpose_v<<<dim3(B_ * 128), blk, 0, stream>>>(VhT, Vt);

  dim3 agrid(B_ * (T_ / 16) * nsplit);
  attn_mfma<<<agrid, blk, 0, stream>>>(Qh, Ql, Kh, Kl, Vt, OP, nsplit);

  // Wo cast (Woh slab is independent; Ql must stay live through attn)
  cast_plain2<<<dim3(nW / 1024), blk, 0, stream>>>(nullptr, nullptr, 0, Wo, Woh, nW);

  reduce_oh<<<dim3((unsigned)(nBTC / 2048)), blk, 0, stream>>>(OP, AOh, nsplit, nBTC);

  // output projection (plain f16) + bias
  mfma_gemm<<<ggrid, blk, 0, stream>>>(AOh, nullptr, Woh, nullptr, M, C_, C_, 0,
                                       out, bo, nullptr, nullptr, 2);
}

// Round 7
// 389.499 us; speedup vs baseline: 7.0283x; 1.9759x over previous
//
#include <hip/hip_runtime.h>
#include <cmath>

namespace {

constexpr int B_ = 2;
constexpr int T_ = 2048;
constexpr int C_ = 1024;
constexpr int H_ = 16;
constexpr int D_ = 64;

typedef _Float16 half8 __attribute__((ext_vector_type(8)));
typedef _Float16 half4 __attribute__((ext_vector_type(4)));
typedef float f32x4 __attribute__((ext_vector_type(4)));

__device__ inline f32x4 vmax4(f32x4 a, f32x4 b) {
  f32x4 r;
  r[0] = fmaxf(a[0], b[0]); r[1] = fmaxf(a[1], b[1]);
  r[2] = fmaxf(a[2], b[2]); r[3] = fmaxf(a[3], b[3]);
  return r;
}

__device__ __forceinline__ void gload16(const _Float16* g, _Float16* l) {
  __builtin_amdgcn_global_load_lds(
      (const __attribute__((address_space(1))) unsigned int*)g,
      (__attribute__((address_space(3))) unsigned int*)l, 16, 0, 0);
}

// ---------------------------------------------------------------------------
// Fused cast: 7 fp32 arrays -> f16 (xq,xk,xv: 4M els; Wq,Wk,Wv,Wo: 1M els).
// ---------------------------------------------------------------------------
__global__ __launch_bounds__(256)
void cast7(const float* __restrict__ xq, const float* __restrict__ xk,
           const float* __restrict__ xv, const float* __restrict__ wq,
           const float* __restrict__ wk, const float* __restrict__ wv,
           const float* __restrict__ wo,
           _Float16* __restrict__ dxq, _Float16* __restrict__ dxk,
           _Float16* __restrict__ dxv, _Float16* __restrict__ dwq,
           _Float16* __restrict__ dwk, _Float16* __restrict__ dwv,
           _Float16* __restrict__ dwo) {
  constexpr size_t NX = (size_t)4 << 20;
  constexpr size_t NW = (size_t)1 << 20;
  size_t g = ((size_t)blockIdx.x * 256 + threadIdx.x) * 8;
  const float* s; _Float16* d; size_t off;
  if      (g <     NX)          { s = xq; d = dxq; off = g; }
  else if (g < 2 * NX)          { s = xk; d = dxk; off = g - NX; }
  else if (g < 3 * NX)          { s = xv; d = dxv; off = g - 2 * NX; }
  else if (g < 3 * NX + NW)     { s = wq; d = dwq; off = g - 3 * NX; }
  else if (g < 3 * NX + 2 * NW) { s = wk; d = dwk; off = g - 3 * NX - NW; }
  else if (g < 3 * NX + 3 * NW) { s = wv; d = dwv; off = g - 3 * NX - 2 * NW; }
  else                          { s = wo; d = dwo; off = g - 3 * NX - 3 * NW; }
  const float4 a = *(const float4*)(s + off);
  const float4 b = *(const float4*)(s + off + 4);
  half8 h;
  h[0] = (_Float16)a.x; h[1] = (_Float16)a.y; h[2] = (_Float16)a.z; h[3] = (_Float16)a.w;
  h[4] = (_Float16)b.x; h[5] = (_Float16)b.y; h[6] = (_Float16)b.z; h[7] = (_Float16)b.w;
  *(half8*)(d + off) = h;
}

// ---------------------------------------------------------------------------
// LDS-staged f16 NT GEMM (m97 structure): Y[m][n] = sum_k A[m][k]*W[n][k].
// Tile 128x128, BK=32; 4 waves, each a 64x64 quadrant (4x4 16x16x32 MFMAs).
// Staging: global_load_lds width=16, XOR chunk swizzle (row R, phys chunk p
// holds logical chunk p ^ ((R>>1)&3)) -> conflict-free ds_read_b128.
// blockIdx.z selects (A,W,Y) triple (projections batched in one launch).
// mode 0: f16 Y out; mode 2: fp32 out + bias.
// ---------------------------------------------------------------------------
__global__ __launch_bounds__(256, 3)
void gemm_f16nt(const _Float16* __restrict__ A0, const _Float16* __restrict__ A1,
                const _Float16* __restrict__ A2,
                const _Float16* __restrict__ W0, const _Float16* __restrict__ W1,
                const _Float16* __restrict__ W2,
                _Float16* __restrict__ Y0, _Float16* __restrict__ Y1,
                _Float16* __restrict__ Y2,
                float* __restrict__ Yf, const float* __restrict__ bias,
                int K, int N, int mode) {
  __shared__ _Float16 sA[128 * 32];
  __shared__ _Float16 sW[128 * 32];

  const int tid  = threadIdx.x;
  const int lane = tid & 63;
  const int w    = tid >> 6;
  const int l15  = lane & 15;
  const int quad = lane >> 4;
  const int z    = blockIdx.z;
  const _Float16* A = (z == 0) ? A0 : (z == 1) ? A1 : A2;
  const _Float16* W = (z == 0) ? W0 : (z == 1) ? W1 : W2;
  _Float16*       Y = (z == 0) ? Y0 : (z == 1) ? Y1 : Y2;

  const int m0 = blockIdx.y * 128;
  const int n0 = blockIdx.x * 128;

  // staging geometry: wave w stages rows [w*32, w*32+32) of sA and sW
  const int Rb  = lane >> 2;            // row within 16-row segment
  const int pch = lane & 3;             // physical chunk written by this lane
  const int lch = pch ^ ((Rb >> 1) & 3);  // logical chunk to fetch
  const int swr = (l15 >> 1) & 3;         // read-side swizzle term

  f32x4 acc[4][4];
#pragma unroll
  for (int mt = 0; mt < 4; ++mt)
#pragma unroll
    for (int nt = 0; nt < 4; ++nt)
      acc[mt][nt] = (f32x4){0.f, 0.f, 0.f, 0.f};

  const int wm = (w >> 1) * 64;
  const int wn = (w & 1) * 64;

  for (int k0 = 0; k0 < K; k0 += 32) {
    __syncthreads();   // previous iteration's ds_reads done
#pragma unroll
    for (int j = 0; j < 2; ++j) {
      const int seg = w * 32 + j * 16;
      gload16(A + (size_t)(m0 + seg + Rb) * K + k0 + lch * 8, &sA[seg * 32]);
      gload16(W + (size_t)(n0 + seg + Rb) * K + k0 + lch * 8, &sW[seg * 32]);
    }
    __syncthreads();   // drains vmcnt: staged tile visible

    half8 af[4], wf[4];
#pragma unroll
    for (int mt = 0; mt < 4; ++mt) {
      const int R = wm + mt * 16 + l15;
      af[mt] = *(const half8*)&sA[R * 32 + (quad ^ swr) * 8];
    }
#pragma unroll
    for (int nt = 0; nt < 4; ++nt) {
      const int R = wn + nt * 16 + l15;
      wf[nt] = *(const half8*)&sW[R * 32 + (quad ^ swr) * 8];
    }
#pragma unroll
    for (int mt = 0; mt < 4; ++mt)
#pragma unroll
      for (int nt = 0; nt < 4; ++nt)
        acc[mt][nt] = __builtin_amdgcn_mfma_f32_16x16x32_f16(wf[nt], af[mt], acc[mt][nt], 0, 0, 0);
  }

#pragma unroll
  for (int mt = 0; mt < 4; ++mt)
#pragma unroll
    for (int nt = 0; nt < 4; ++nt) {
      const int m = m0 + wm + mt * 16 + l15;
      const int n = n0 + wn + nt * 16 + quad * 4;
      if (mode == 2) {
        float4 v;
        v.x = acc[mt][nt][0] + bias[n + 0];
        v.y = acc[mt][nt][1] + bias[n + 1];
        v.z = acc[mt][nt][2] + bias[n + 2];
        v.w = acc[mt][nt][3] + bias[n + 3];
        *(float4*)(Yf + (size_t)m * N + n) = v;
      } else {
        half4 hv;
#pragma unroll
        for (int r = 0; r < 4; ++r) hv[r] = (_Float16)acc[mt][nt][r];
        *(half4*)(Y + (size_t)m * N + n) = hv;
      }
    }
}

// ---------------------------------------------------------------------------
// V pretranspose: Vh[b][t][c] -> Vt[b][h][kt][d][k16]  (f16, 8 MB)
// ---------------------------------------------------------------------------
__global__ __launch_bounds__(256)
void transpose_v(const _Float16* __restrict__ Vh, _Float16* __restrict__ Vt) {
  constexpr int PAD = 1028;
  __shared__ _Float16 tile[16][PAD];
  const int b  = blockIdx.x >> 7;
  const int kt = blockIdx.x & 127;
  const int tid = threadIdx.x;

#pragma unroll
  for (int j = 0; j < 8; ++j) {
    const int ch = tid + 256 * j;
    const int t  = ch >> 7;
    const int c8 = ch & 127;
    *(half8*)&tile[t][c8 * 8] =
        *(const half8*)(Vh + ((size_t)b * T_ + kt * 16 + t) * C_ + c8 * 8);
  }
  __syncthreads();

#pragma unroll
  for (int j = 0; j < 8; ++j) {
    const int cc = tid + 256 * j;
    const int h  = cc >> 7;
    const int d  = (cc >> 1) & 63;
    const int th = (cc & 1) * 8;
    half8 v;
#pragma unroll
    for (int i = 0; i < 8; ++i) v[i] = tile[th + i][h * 64 + d];
    *(half8*)(Vt + ((((size_t)b * H_ + h) * 128 + kt) * 64 + d) * 16 + th) = v;
  }
}

// ---------------------------------------------------------------------------
// MFMA head-softmax attention v4: plain f16 Q/K (error budget: logit err
// ~1e-2 << softmax scale), Q fragments hoisted to registers (loop-invariant),
// 24 loads + 24 MFMA per 16-key tile, ping-pong reduction LDS.
// ---------------------------------------------------------------------------
__global__ __launch_bounds__(256, 2)
void attn_mfma(const _Float16* __restrict__ Qhp, const _Float16* __restrict__ Khp,
               const _Float16* __restrict__ Vtp, _Float16* __restrict__ OP,
               int nsplit) {
  __shared__ f32x4 red[2][2][4][64];

  const int tid  = threadIdx.x;
  const int lane = tid & 63;
  const int w    = tid >> 6;
  const int l15  = lane & 15;
  const int quad = lane >> 4;
  const int cell = quad * 16 + l15;

  const int nbq   = B_ * (T_ / 16);
  const int split = blockIdx.x / nbq;
  const int bq    = blockIdx.x % nbq;
  const int b  = bq >> 7;
  const int q0 = (bq & 127) << 4;

  const size_t qrow = ((size_t)b * T_ + q0 + l15) * C_;

  // hoisted Q fragments (loop-invariant): 8 half8 = 32 VGPR
  half8 qh[4][2];
#pragma unroll
  for (int hl = 0; hl < 4; ++hl)
#pragma unroll
    for (int kk = 0; kk < 2; ++kk)
      qh[hl][kk] = *(const half8*)(Qhp + qrow + (w * 4 + hl) * 64 + kk * 32 + quad * 8);

  f32x4 oacc[4][4];
#pragma unroll
  for (int hl = 0; hl < 4; ++hl)
#pragma unroll
    for (int mt = 0; mt < 4; ++mt)
      oacc[hl][mt] = (f32x4){0.f, 0.f, 0.f, 0.f};

  const int kpb  = T_ / nsplit;
  const int k_lo = split * kpb;
  const int jt   = kpb / 16;

  for (int j = 0; j < jt; ++j) {
    const int k0 = k_lo + j * 16;
    const int p  = j & 1;
    const int kt = k0 >> 4;
    const size_t krow = ((size_t)b * T_ + k0 + l15) * C_;

    // batched loads: 8 K half8 + 16 V half4 in flight together
    half8 akh[4][2];
    half4 avf[4][4];
#pragma unroll
    for (int hl = 0; hl < 4; ++hl)
#pragma unroll
      for (int kk = 0; kk < 2; ++kk)
        akh[hl][kk] = *(const half8*)(Khp + krow + (w * 4 + hl) * 64 + kk * 32 + quad * 8);
#pragma unroll
    for (int hl = 0; hl < 4; ++hl) {
      const _Float16* vb =
          Vtp + (((size_t)b * H_ + (w * 4 + hl)) * 128 + kt) * 1024;
#pragma unroll
      for (int mt = 0; mt < 4; ++mt)
        avf[hl][mt] = *(const half4*)(vb + (mt * 16 + l15) * 16 + quad * 4);
    }

    // S^T = K Q^T, * sqrt(D)=8 quirk
    f32x4 s[4];
#pragma unroll
    for (int hl = 0; hl < 4; ++hl) s[hl] = (f32x4){0.f, 0.f, 0.f, 0.f};
#pragma unroll
    for (int hl = 0; hl < 4; ++hl)
#pragma unroll
      for (int kk = 0; kk < 2; ++kk)
        s[hl] = __builtin_amdgcn_mfma_f32_16x16x32_f16(akh[hl][kk], qh[hl][kk], s[hl], 0, 0, 0);
#pragma unroll
    for (int hl = 0; hl < 4; ++hl) s[hl] = s[hl] * 8.f;

    // head-softmax, ping-pong LDS: 2 barriers/tile
    red[p][0][w][cell] = vmax4(vmax4(s[0], s[1]), vmax4(s[2], s[3]));
    __syncthreads();
    const f32x4 gmax = vmax4(vmax4(red[p][0][0][cell], red[p][0][1][cell]),
                             vmax4(red[p][0][2][cell], red[p][0][3][cell]));
    float e[4][4];
    f32x4 ps = (f32x4){0.f, 0.f, 0.f, 0.f};
#pragma unroll
    for (int hl = 0; hl < 4; ++hl)
#pragma unroll
      for (int r = 0; r < 4; ++r) {
        e[hl][r] = __expf(s[hl][r] - gmax[r]);
        ps[r] += e[hl][r];
      }
    red[p][1][w][cell] = ps;
    __syncthreads();
    const f32x4 gs = red[p][1][0][cell] + red[p][1][1][cell] +
                     red[p][1][2][cell] + red[p][1][3][cell];
    f32x4 inv;
#pragma unroll
    for (int r = 0; r < 4; ++r) inv[r] = 1.f / gs[r];

    half4 pf[4];
#pragma unroll
    for (int hl = 0; hl < 4; ++hl)
#pragma unroll
      for (int r = 0; r < 4; ++r)
        pf[hl][r] = (_Float16)(e[hl][r] * inv[r]);

    // O^T += V^T P^T (V frags resident)
#pragma unroll
    for (int hl = 0; hl < 4; ++hl)
#pragma unroll
      for (int mt = 0; mt < 4; ++mt)
        oacc[hl][mt] =
            __builtin_amdgcn_mfma_f32_16x16x16f16(avf[hl][mt], pf[hl], oacc[hl][mt], 0, 0, 0);
  }

  _Float16* op = OP + (size_t)split * ((size_t)B_ * T_ * C_);
  const size_t orow = ((size_t)b * T_ + q0 + l15) * C_;
#pragma unroll
  for (int hl = 0; hl < 4; ++hl)
#pragma unroll
    for (int mt = 0; mt < 4; ++mt) {
      half4 hv;
#pragma unroll
      for (int r = 0; r < 4; ++r) hv[r] = (_Float16)oacc[hl][mt][r];
      *(half4*)(op + orow + (w * 4 + hl) * 64 + mt * 16 + quad * 4) = hv;
    }
}

// ---------------------------------------------------------------------------
// AOh = (f16) sum over splits of f16 OP[s]  (fp32 accumulate)
// ---------------------------------------------------------------------------
__global__ __launch_bounds__(256)
void reduce_oh(const _Float16* __restrict__ OP, _Float16* __restrict__ AOh,
               int nsplit, size_t n) {
  const size_t i = ((size_t)blockIdx.x * 256 + threadIdx.x) * 8;
  float a[8] = {};
  for (int s = 0; s < nsplit; ++s) {
    const half8 v = *(const half8*)(OP + (size_t)s * n + i);
#pragma unroll
    for (int r = 0; r < 8; ++r) a[r] += (float)v[r];
  }
  half8 o;
#pragma unroll
  for (int r = 0; r < 8; ++r) o[r] = (_Float16)a[r];
  *(half8*)(AOh + i) = o;
}

}  // namespace

extern "C" void kernel_launch(void* const* d_in, const int* in_sizes, int n_in,
                              void* d_out, int out_size, void* d_ws, size_t ws_size,
                              hipStream_t stream) {
  const float* xq = (const float*)d_in[0];
  const float* xk = (const float*)d_in[1];
  const float* xv = (const float*)d_in[2];
  const float* Wq = (const float*)d_in[3];
  const float* Wk = (const float*)d_in[4];
  const float* Wv = (const float*)d_in[5];
  const float* Wo = (const float*)d_in[6];
  const float* bo = (const float*)d_in[7];
  float* out = (float*)d_out;

  const size_t MB   = 1ull << 20;
  const size_t nBTC = (size_t)B_ * T_ * C_;  // 4M elements

  // workspace (MB):
  //  [0,8) Qh  [8,16) Kh  [16,24) Vt  [24,32) vh (pre-transpose; AOh after attn)
  //  [32,40) xqh [40,48) xkh [48,56) xvh   (dead after proj)
  //  attn: OP f16 partials [32,64)  (nsplit=4)
  //  [64,66) Wqh [66,68) Wkh [68,70) Wvh [70,72) Woh
  char* wsb = (char*)d_ws;
  _Float16* Qh  = (_Float16*)(wsb + 0 * MB);
  _Float16* Kh  = (_Float16*)(wsb + 8 * MB);
  _Float16* Vt  = (_Float16*)(wsb + 16 * MB);
  _Float16* vh  = (_Float16*)(wsb + 24 * MB);
  _Float16* AOh = (_Float16*)(wsb + 24 * MB);
  _Float16* xqh = (_Float16*)(wsb + 32 * MB);
  _Float16* xkh = (_Float16*)(wsb + 40 * MB);
  _Float16* xvh = (_Float16*)(wsb + 48 * MB);
  _Float16* OP  = (_Float16*)(wsb + 32 * MB);
  _Float16* Wqh = (_Float16*)(wsb + 64 * MB);
  _Float16* Wkh = (_Float16*)(wsb + 66 * MB);
  _Float16* Wvh = (_Float16*)(wsb + 68 * MB);
  _Float16* Woh = (_Float16*)(wsb + 70 * MB);

  const int nsplit = 4;
  const int M = B_ * T_;                     // 4096
  dim3 blk(256);

  // 1) cast all 7 fp32 inputs to f16 (16M elements)
  cast7<<<dim3(8192), blk, 0, stream>>>(xq, xk, xv, Wq, Wk, Wv, Wo,
                                        xqh, xkh, xvh, Wqh, Wkh, Wvh, Woh);

  // 2) three projections, z-batched (768 blocks = 3/CU)
  gemm_f16nt<<<dim3(C_ / 128, M / 128, 3), blk, 0, stream>>>(
      xqh, xkh, xvh, Wqh, Wkh, Wvh, Qh, Kh, vh,
      nullptr, nullptr, C_, C_, 0);

  // 3) V pretranspose
  transpose_v<<<dim3(B_ * 128), blk, 0, stream>>>(vh, Vt);

  // 4) fused head-softmax attention (split-k x4)
  attn_mfma<<<dim3(B_ * (T_ / 16) * nsplit), blk, 0, stream>>>(Qh, Kh, Vt, OP, nsplit);

  // 5) split reduction -> f16 AO
  reduce_oh<<<dim3((unsigned)(nBTC / 2048)), blk, 0, stream>>>(OP, AOh, nsplit, nBTC);

  // 6) output projection + bias -> fp32 out
  gemm_f16nt<<<dim3(C_ / 128, M / 128, 1), blk, 0, stream>>>(
      AOh, nullptr, nullptr, Woh, nullptr, nullptr, nullptr, nullptr, nullptr,
      out, bo, C_, C_, 2);
}